// Round 1
// baseline (2483.390 us; speedup 1.0000x reference)
//
#include <hip/hip_runtime.h>
#include <math.h>

// Problem constants
// H=256, D_IN=22, T=384, 4H=1024, N_R=N_L=384, H1=1024, H2=512, H3=1024, RRI=2

// ---------------------------------------------------------------------------
// prep: b0sum = bih0+bhh0, b1sum = bih1+bhh1, W3sum[n][k] = W3[n][k]+W3[n][512+k],
//       woutT[2c+k] = Wout[k][c], zero sync flags
// ---------------------------------------------------------------------------
__global__ __launch_bounds__(256) void prep_kernel(
    const float* __restrict__ bih0, const float* __restrict__ bhh0,
    const float* __restrict__ bih1, const float* __restrict__ bhh1,
    const float* __restrict__ W3,   const float* __restrict__ Wout,
    float* __restrict__ b0sum, float* __restrict__ b1sum,
    float* __restrict__ W3sum, float* __restrict__ woutT,
    unsigned int* __restrict__ flags)
{
    int idx = blockIdx.x * 256 + threadIdx.x;
    int stride = gridDim.x * 256;
    if (idx < 2048) {
        b0sum[idx] = bih0[idx] + bhh0[idx];
        b1sum[idx] = bih1[idx] + bhh1[idx];
        woutT[idx] = Wout[(idx & 1) * 1024 + (idx >> 1)];
    }
    if (idx < 32) flags[idx] = 0u;
    for (int i = idx; i < 1024 * 512; i += stride) {
        int n = i >> 9, k = i & 511;
        W3sum[i] = W3[n * 1024 + k] + W3[n * 1024 + 512 + k];
    }
}

// ---------------------------------------------------------------------------
// proj0: pre0[(seq*2+dir)][t][o] = x[t] @ Wih0[dir].T + b0sum[dir]
// grid (384, 4), 256 threads
// ---------------------------------------------------------------------------
__global__ __launch_bounds__(256) void proj0_kernel(
    const float* __restrict__ v_r, const float* __restrict__ v_l,
    const float* __restrict__ Wih0, const float* __restrict__ b0sum,
    float* __restrict__ pre0)
{
    int t = blockIdx.x;
    int sd = blockIdx.y;            // seq*2 + dir
    int seq = sd >> 1, dir = sd & 1;
    const float* x = (seq ? v_l : v_r) + t * 22;
    __shared__ float sx[22];
    if (threadIdx.x < 22) sx[threadIdx.x] = x[threadIdx.x];
    __syncthreads();
#pragma unroll
    for (int q = 0; q < 4; ++q) {
        int o = q * 256 + threadIdx.x;
        const float* wr = Wih0 + (size_t)(dir * 1024 + o) * 22;
        float acc = b0sum[dir * 1024 + o];
#pragma unroll
        for (int d = 0; d < 22; ++d) acc += sx[d] * wr[d];
        pre0[((size_t)sd * 384 + t) * 1024 + o] = acc;
    }
}

// ---------------------------------------------------------------------------
// LSTM recurrence. 16 blocks x 512 threads. block = (chain c in 0..3, slice w in 0..3)
// chain: seq = c>>1 (0=r,1=l), dir = c&1 (0=fwd,1=bwd).
// k-split: slice w covers k in [64w, 64w+64); thread holds Whh rows {tid, tid+512}
// for that slice in registers (128 fp32 VGPRs), resident across all 384 steps.
// Per step: one device-scope flag sync; partials double-buffered in L3 (agent
// atomics); every WG redundantly computes the gate update so there is exactly
// ONE cross-WG round trip per step.
// ---------------------------------------------------------------------------
__global__ __launch_bounds__(512) void lstm_rec_kernel(
    const float* __restrict__ Whh,   // [2][1024][256]
    const float* __restrict__ pre,   // layer0: [seq*2+dir][384][1024]; layer1: [seq*384+t][2][1024]
    float* __restrict__ out,         // [2][384][512]  (cols: dir*256 + j)
    float* P,                        // [4 chains][2 parity][4 slices][1024]
    unsigned int* flags,             // [4 chains][4 slices] for this layer
    int layer)
{
    const int b = blockIdx.x;
    const int chain = b >> 2, w = b & 3;
    const int seq = chain >> 1, dir = chain & 1;
    const int tid = threadIdx.x;
    __shared__ __align__(16) float hs[256];

    // Load this thread's weight slice into registers (once).
    float wA[64], wB[64];
    {
        const float* r0 = Whh + (size_t)(dir * 1024 + tid) * 256 + (w << 6);
        const float* r1 = Whh + (size_t)(dir * 1024 + 512 + tid) * 256 + (w << 6);
#pragma unroll
        for (int q = 0; q < 16; ++q) {
            float4 a = *(const float4*)(r0 + 4 * q);
            float4 c = *(const float4*)(r1 + 4 * q);
            wA[4*q+0] = a.x; wA[4*q+1] = a.y; wA[4*q+2] = a.z; wA[4*q+3] = a.w;
            wB[4*q+0] = c.x; wB[4*q+1] = c.y; wB[4*q+2] = c.z; wB[4*q+3] = c.w;
        }
    }
    if (tid < 256) hs[tid] = 0.f;
    float cstate = 0.f;
    __syncthreads();

    float* Pc = P + (size_t)chain * 2 * 4 * 1024;
    unsigned int* fl = flags + chain * 4;

    for (int s = 0; s < 384; ++s) {
        const int t = dir ? (383 - s) : s;
        // Prefetch pre-activations for the update phase (hides L2/L3 latency
        // behind phase 1 compute).
        const float* pre_t = (layer == 0)
            ? pre + ((size_t)(seq * 2 + dir) * 384 + t) * 1024
            : pre + (((size_t)(seq * 384 + t)) * 2 + dir) * 1024;
        float p0 = 0.f, p1 = 0.f, p2 = 0.f, p3 = 0.f;
        if (tid < 256) {
            p0 = pre_t[tid];
            p1 = pre_t[256 + tid];
            p2 = pre_t[512 + tid];
            p3 = pre_t[768 + tid];
        }

        // Phase 1: partial matvec over this WG's k-slice (h from LDS, broadcast).
        float ax0 = 0.f, ax1 = 0.f, ay0 = 0.f, ay1 = 0.f;
        const float4* h4 = (const float4*)hs + (w << 4);
#pragma unroll
        for (int q = 0; q < 16; ++q) {
            float4 hv = h4[q];
            ax0 += wA[4*q+0] * hv.x; ay0 += wB[4*q+0] * hv.x;
            ax1 += wA[4*q+1] * hv.y; ay1 += wB[4*q+1] * hv.y;
            ax0 += wA[4*q+2] * hv.z; ay0 += wB[4*q+2] * hv.z;
            ax1 += wA[4*q+3] * hv.w; ay1 += wB[4*q+3] * hv.w;
        }
        float* Pp = Pc + ((size_t)(s & 1) * 4 + w) * 1024;
        __hip_atomic_store(&Pp[tid],       ax0 + ax1, __ATOMIC_RELAXED, __HIP_MEMORY_SCOPE_AGENT);
        __hip_atomic_store(&Pp[tid + 512], ay0 + ay1, __ATOMIC_RELAXED, __HIP_MEMORY_SCOPE_AGENT);
        __syncthreads();   // drains vmcnt: all partial stores globally visible

        if (tid == 0)
            __hip_atomic_store(&fl[w], (unsigned)(s + 1), __ATOMIC_RELEASE, __HIP_MEMORY_SCOPE_AGENT);
        if (tid < 3) {
            const unsigned int* f = &fl[(w + 1 + tid) & 3];
            while (__hip_atomic_load(f, __ATOMIC_ACQUIRE, __HIP_MEMORY_SCOPE_AGENT) < (unsigned)(s + 1))
                __builtin_amdgcn_s_sleep(1);
        }
        __syncthreads();

        // Phase 2: every WG redundantly computes the full gate update.
        if (tid < 256) {
            float* Pb = Pc + (size_t)(s & 1) * 4 * 1024;
            float gi = p0, gf = p1, gg = p2, go = p3;
#pragma unroll
            for (int w2 = 0; w2 < 4; ++w2) {
                gi += __hip_atomic_load(&Pb[w2 * 1024 +       tid], __ATOMIC_RELAXED, __HIP_MEMORY_SCOPE_AGENT);
                gf += __hip_atomic_load(&Pb[w2 * 1024 + 256 + tid], __ATOMIC_RELAXED, __HIP_MEMORY_SCOPE_AGENT);
                gg += __hip_atomic_load(&Pb[w2 * 1024 + 512 + tid], __ATOMIC_RELAXED, __HIP_MEMORY_SCOPE_AGENT);
                go += __hip_atomic_load(&Pb[w2 * 1024 + 768 + tid], __ATOMIC_RELAXED, __HIP_MEMORY_SCOPE_AGENT);
            }
            float ig = 1.f / (1.f + expf(-gi));
            float fg = 1.f / (1.f + expf(-gf));
            float gv = tanhf(gg);
            float og = 1.f / (1.f + expf(-go));
            cstate = fg * cstate + ig * gv;
            float h = og * tanhf(cstate);
            hs[tid] = h;
            if (w == 0)
                out[((size_t)seq * 384 + t) * 512 + dir * 256 + tid] = h;
        }
        __syncthreads();
    }
}

// ---------------------------------------------------------------------------
// Generic NT GEMM: C[M][N] = act(scale * A[M][K] @ W[N][K]^T + bias[N])
// 64x64 tile per 256-thread block, K-chunks of 32, LDS staged transposed.
// ---------------------------------------------------------------------------
__global__ __launch_bounds__(256) void gemm_nt_kernel(
    const float* __restrict__ A, const float* __restrict__ W,
    const float* __restrict__ bias, float* __restrict__ C,
    int M, int N, int K, float scale, int do_relu)
{
    __shared__ float As[32][68];
    __shared__ float Ws[32][68];
    const int tid = threadIdx.x;
    const int n0 = blockIdx.x * 64, m0 = blockIdx.y * 64;
    const int lr = tid >> 2;            // 0..63 tile row
    const int lk = (tid & 3) * 8;       // k sub-offset
    const int tm = tid >> 4, tn = tid & 15;
    float acc[4][4];
#pragma unroll
    for (int i = 0; i < 4; ++i)
#pragma unroll
        for (int j = 0; j < 4; ++j) acc[i][j] = 0.f;

    for (int kc = 0; kc < K; kc += 32) {
        float4 a0 = *(const float4*)(A + (size_t)(m0 + lr) * K + kc + lk);
        float4 a1 = *(const float4*)(A + (size_t)(m0 + lr) * K + kc + lk + 4);
        float4 w0 = *(const float4*)(W + (size_t)(n0 + lr) * K + kc + lk);
        float4 w1 = *(const float4*)(W + (size_t)(n0 + lr) * K + kc + lk + 4);
        __syncthreads();
        As[lk + 0][lr] = a0.x; As[lk + 1][lr] = a0.y; As[lk + 2][lr] = a0.z; As[lk + 3][lr] = a0.w;
        As[lk + 4][lr] = a1.x; As[lk + 5][lr] = a1.y; As[lk + 6][lr] = a1.z; As[lk + 7][lr] = a1.w;
        Ws[lk + 0][lr] = w0.x; Ws[lk + 1][lr] = w0.y; Ws[lk + 2][lr] = w0.z; Ws[lk + 3][lr] = w0.w;
        Ws[lk + 4][lr] = w1.x; Ws[lk + 5][lr] = w1.y; Ws[lk + 6][lr] = w1.z; Ws[lk + 7][lr] = w1.w;
        __syncthreads();
#pragma unroll
        for (int kk = 0; kk < 32; ++kk) {
            float4 av = *(const float4*)&As[kk][tm * 4];
            float4 wv = *(const float4*)&Ws[kk][tn * 4];
            acc[0][0] += av.x * wv.x; acc[0][1] += av.x * wv.y; acc[0][2] += av.x * wv.z; acc[0][3] += av.x * wv.w;
            acc[1][0] += av.y * wv.x; acc[1][1] += av.y * wv.y; acc[1][2] += av.y * wv.z; acc[1][3] += av.y * wv.w;
            acc[2][0] += av.z * wv.x; acc[2][1] += av.z * wv.y; acc[2][2] += av.z * wv.z; acc[2][3] += av.z * wv.w;
            acc[3][0] += av.w * wv.x; acc[3][1] += av.w * wv.y; acc[3][2] += av.w * wv.z; acc[3][3] += av.w * wv.w;
        }
    }
    float4 bv = make_float4(0.f, 0.f, 0.f, 0.f);
    if (bias) bv = *(const float4*)(bias + n0 + tn * 4);
#pragma unroll
    for (int i = 0; i < 4; ++i) {
        int m = m0 + tm * 4 + i;
        float4 v;
        v.x = scale * acc[i][0] + bv.x;
        v.y = scale * acc[i][1] + bv.y;
        v.z = scale * acc[i][2] + bv.z;
        v.w = scale * acc[i][3] + bv.w;
        if (do_relu) {
            v.x = fmaxf(v.x, 0.f); v.y = fmaxf(v.y, 0.f);
            v.z = fmaxf(v.z, 0.f); v.w = fmaxf(v.w, 0.f);
        }
        *(float4*)(C + (size_t)m * N + n0 + tn * 4) = v;
    }
}

// ---------------------------------------------------------------------------
// pairwise: out[i][j][k] = log_softmax_k( sum_c relu(ur'[i][c]+ul[j][c]) * Wout[k][c] + bout[k] )
// u rows 0..383 = ur' (b3 folded in), rows 384..767 = ul. 32x32 pair tile per
// 256-thread block (2x2 pairs/thread), c-chunks of 128 staged in LDS.
// ---------------------------------------------------------------------------
__global__ __launch_bounds__(256) void pairwise_kernel(
    const float* __restrict__ u,      // [768][1024]
    const float* __restrict__ woutT,  // [1024][2]
    const float* __restrict__ bout,   // [2]
    float* __restrict__ out)          // [384][384][2]
{
    __shared__ float Ur[32][128];
    __shared__ float Ul[32][128];
    __shared__ float Wo[256];
    const int tid = threadIdx.x;
    const int j0 = blockIdx.x * 32, i0 = blockIdx.y * 32;
    const int ii = tid >> 4, jj = tid & 15;
    const int il0 = ii * 2, il1 = ii * 2 + 1;
    const int jl0 = jj * 2, jl1 = jj * 2 + 1;
    float acc000 = 0.f, acc001 = 0.f, acc010 = 0.f, acc011 = 0.f;
    float acc100 = 0.f, acc101 = 0.f, acc110 = 0.f, acc111 = 0.f;
    const int lrw = tid >> 3;           // 0..31
    const int lcb = (tid & 7) * 16;     // 0..112

    for (int cc = 0; cc < 1024; cc += 128) {
        __syncthreads();
#pragma unroll
        for (int q = 0; q < 4; ++q) {
            *(float4*)&Ur[lrw][lcb + 4 * q] =
                *(const float4*)(u + (size_t)(i0 + lrw) * 1024 + cc + lcb + 4 * q);
            *(float4*)&Ul[lrw][lcb + 4 * q] =
                *(const float4*)(u + (size_t)(384 + j0 + lrw) * 1024 + cc + lcb + 4 * q);
        }
        if (tid < 128)
            *(float2*)&Wo[tid * 2] = *(const float2*)(woutT + (size_t)(cc + tid) * 2);
        __syncthreads();

        for (int c = 0; c < 128; c += 4) {
            float4 a0  = *(const float4*)&Ur[il0][c];
            float4 a1  = *(const float4*)&Ur[il1][c];
            float4 b0v = *(const float4*)&Ul[jl0][c];
            float4 b1v = *(const float4*)&Ul[jl1][c];
            float4 wA4 = *(const float4*)&Wo[c * 2];
            float4 wB4 = *(const float4*)&Wo[c * 2 + 4];
#define PW_STEP(AX, W0, W1)                                   \
            { float r;                                        \
              r = fmaxf(a0.AX + b0v.AX, 0.f); acc000 += r*(W0); acc001 += r*(W1); \
              r = fmaxf(a0.AX + b1v.AX, 0.f); acc010 += r*(W0); acc011 += r*(W1); \
              r = fmaxf(a1.AX + b0v.AX, 0.f); acc100 += r*(W0); acc101 += r*(W1); \
              r = fmaxf(a1.AX + b1v.AX, 0.f); acc110 += r*(W0); acc111 += r*(W1); }
            PW_STEP(x, wA4.x, wA4.y)
            PW_STEP(y, wA4.z, wA4.w)
            PW_STEP(z, wB4.x, wB4.y)
            PW_STEP(w, wB4.z, wB4.w)
#undef PW_STEP
        }
    }
    float2 bo = *(const float2*)bout;
    float pa[2][2][2] = {{{acc000, acc001}, {acc010, acc011}},
                         {{acc100, acc101}, {acc110, acc111}}};
#pragma unroll
    for (int pi = 0; pi < 2; ++pi)
#pragma unroll
        for (int pj = 0; pj < 2; ++pj) {
            float l0 = pa[pi][pj][0] + bo.x;
            float l1 = pa[pi][pj][1] + bo.y;
            float m = fmaxf(l0, l1);
            float lse = m + logf(expf(l0 - m) + expf(l1 - m));
            int ig = i0 + il0 + pi;
            int jg = j0 + jl0 + pj;
            float2 o2; o2.x = l0 - lse; o2.y = l1 - lse;
            *(float2*)(out + ((size_t)ig * 384 + jg) * 2) = o2;
        }
}

// ---------------------------------------------------------------------------
extern "C" void kernel_launch(void* const* d_in, const int* in_sizes, int n_in,
                              void* d_out, int out_size, void* d_ws, size_t ws_size,
                              hipStream_t stream)
{
    const float* v_r  = (const float*)d_in[0];
    const float* v_l  = (const float*)d_in[1];
    const float* Wih0 = (const float*)d_in[2];
    const float* Whh0 = (const float*)d_in[3];
    const float* bih0 = (const float*)d_in[4];
    const float* bhh0 = (const float*)d_in[5];
    const float* Wih1 = (const float*)d_in[6];
    const float* Whh1 = (const float*)d_in[7];
    const float* bih1 = (const float*)d_in[8];
    const float* bhh1 = (const float*)d_in[9];
    const float* W1   = (const float*)d_in[10];
    const float* b1   = (const float*)d_in[11];
    const float* W2   = (const float*)d_in[12];
    const float* b2   = (const float*)d_in[13];
    const float* W3   = (const float*)d_in[14];
    const float* b3   = (const float*)d_in[15];
    const float* Wout = (const float*)d_in[16];
    const float* bout = (const float*)d_in[17];
    float* out = (float*)d_out;

    float* ws = (float*)d_ws;
    size_t off = 0;
    float* b0sum = ws + off; off += 2048;
    float* b1sum = ws + off; off += 2048;
    float* W3sum = ws + off; off += 1024 * 512;
    float* woutT = ws + off; off += 2048;
    float* pre0  = ws + off; off += (size_t)4 * 384 * 1024;   // [seq*2+dir][384][1024]
    float* out0  = ws + off; off += (size_t)2 * 384 * 512;    // layer0 bilstm out
    float* pre1  = ws + off; off += (size_t)768 * 2048;       // [seq*384+t][dir*1024+o]
    float* out1  = ws + off; off += (size_t)2 * 384 * 512;    // layer1 bilstm out
    float* h1    = ws + off; off += (size_t)768 * 1024;
    float* h2    = ws + off; off += (size_t)768 * 512;
    float* u     = ws + off; off += (size_t)768 * 1024;       // rows 0..383 ur'(+b3), 384..767 ul
    float* P     = ws + off; off += 4 * 2 * 4 * 1024;
    unsigned int* flags = (unsigned int*)(ws + off); off += 32;

    prep_kernel<<<512, 256, 0, stream>>>(bih0, bhh0, bih1, bhh1, W3, Wout,
                                         b0sum, b1sum, W3sum, woutT, flags);
    proj0_kernel<<<dim3(384, 4), 256, 0, stream>>>(v_r, v_l, Wih0, b0sum, pre0);
    lstm_rec_kernel<<<16, 512, 0, stream>>>(Whh0, pre0, out0, P, flags, 0);
    // pre1 = out0 @ Wih1(stacked [2048,512])^T + b1sum
    gemm_nt_kernel<<<dim3(2048 / 64, 768 / 64), 256, 0, stream>>>(
        out0, Wih1, b1sum, pre1, 768, 2048, 512, 1.f, 0);
    lstm_rec_kernel<<<16, 512, 0, stream>>>(Whh1, pre1, out1, P, flags + 16, 1);
    // MLP
    gemm_nt_kernel<<<dim3(1024 / 64, 768 / 64), 256, 0, stream>>>(
        out1, W1, b1, h1, 768, 1024, 512, 1.f, 1);
    gemm_nt_kernel<<<dim3(512 / 64, 768 / 64), 256, 0, stream>>>(
        h1, W2, b2, h2, 768, 512, 1024, 1.f, 1);
    // u_r' = 0.5*(h2_r @ W3sum^T) + b3 ; u_l = 0.5*(h2_l @ W3sum^T)
    gemm_nt_kernel<<<dim3(1024 / 64, 384 / 64), 256, 0, stream>>>(
        h2, W3sum, b3, u, 384, 1024, 512, 0.5f, 0);
    gemm_nt_kernel<<<dim3(1024 / 64, 384 / 64), 256, 0, stream>>>(
        h2 + (size_t)384 * 512, W3sum, nullptr, u + (size_t)384 * 1024, 384, 1024, 512, 0.5f, 0);
    pairwise_kernel<<<dim3(12, 12), 256, 0, stream>>>(u, woutT, bout, out);
}

// Round 2
// 2122.079 us; speedup vs baseline: 1.1703x; 1.1703x over previous
//
#include <hip/hip_runtime.h>
#include <math.h>

// Problem constants
// H=256, D_IN=22, T=384, 4H=1024, N_R=N_L=384, H1=1024, H2=512, H3=1024, RRI=2

// ---------------------------------------------------------------------------
// prep: b0sum = bih0+bhh0, b1sum = bih1+bhh1, W3sum[n][k] = W3[n][k]+W3[n][512+k],
//       woutT[2c+k] = Wout[k][c]
// ---------------------------------------------------------------------------
__global__ __launch_bounds__(256) void prep_kernel(
    const float* __restrict__ bih0, const float* __restrict__ bhh0,
    const float* __restrict__ bih1, const float* __restrict__ bhh1,
    const float* __restrict__ W3,   const float* __restrict__ Wout,
    float* __restrict__ b0sum, float* __restrict__ b1sum,
    float* __restrict__ W3sum, float* __restrict__ woutT)
{
    int idx = blockIdx.x * 256 + threadIdx.x;
    int stride = gridDim.x * 256;
    if (idx < 2048) {
        b0sum[idx] = bih0[idx] + bhh0[idx];
        b1sum[idx] = bih1[idx] + bhh1[idx];
        woutT[idx] = Wout[(idx & 1) * 1024 + (idx >> 1)];
    }
    for (int i = idx; i < 1024 * 512; i += stride) {
        int n = i >> 9, k = i & 511;
        W3sum[i] = W3[n * 1024 + k] + W3[n * 1024 + 512 + k];
    }
}

// ---------------------------------------------------------------------------
// proj0: pre0[(seq*2+dir)][t][o] = x[t] @ Wih0[dir].T + b0sum[dir]
// ---------------------------------------------------------------------------
__global__ __launch_bounds__(256) void proj0_kernel(
    const float* __restrict__ v_r, const float* __restrict__ v_l,
    const float* __restrict__ Wih0, const float* __restrict__ b0sum,
    float* __restrict__ pre0)
{
    int t = blockIdx.x;
    int sd = blockIdx.y;            // seq*2 + dir
    int seq = sd >> 1, dir = sd & 1;
    const float* x = (seq ? v_l : v_r) + t * 22;
    __shared__ float sx[22];
    if (threadIdx.x < 22) sx[threadIdx.x] = x[threadIdx.x];
    __syncthreads();
#pragma unroll
    for (int q = 0; q < 4; ++q) {
        int o = q * 256 + threadIdx.x;
        const float* wr = Wih0 + (size_t)(dir * 1024 + o) * 22;
        float acc = b0sum[dir * 1024 + o];
#pragma unroll
        for (int d = 0; d < 22; ++d) acc += sx[d] * wr[d];
        pre0[((size_t)sd * 384 + t) * 1024 + o] = acc;
    }
}

// ---------------------------------------------------------------------------
// LSTM recurrence, v2: OUTPUT-split (not K-split).
// 16 blocks x 512 threads; block = (chain in 0..3, w in 0..3).
// WG (chain,w) owns output slice j in [64w,64w+64) of ALL 4 gates over FULL
// k=256 -> h-slice computed entirely locally; cross-WG exchange is only the
// 64-float h-slice per step. Step tag embedded in an 8-byte atomic
// (tag<<32|h_bits): readers spin on the DATA itself -> ONE device-scope round
// trip per step, no flags, no release fence. Parity double-buffer is safe:
// publishing step s+2 implies all WGs consumed all step-s values.
// Thread t: row r=t>>1 (gate g=r>>6, jloc=r&63), k-half = t&1.
// Weights: 128 fp32 VGPRs, register-resident (launch_bounds(512,2) -> 256 cap).
// ---------------------------------------------------------------------------
__global__ __launch_bounds__(512, 2) void lstm_rec_kernel(
    const float* __restrict__ Whh,   // [2][1024][256]
    const float* __restrict__ pre,   // layer0: [(seq*2+dir)][384][1024]; layer1: [(seq*384+t)][2][1024]
    float* __restrict__ out,         // [2][384][512]  (cols: dir*256 + j)
    unsigned long long* pub,         // [4 chains][2 parity][4 w][64]
    int layer)
{
    const int b = blockIdx.x;
    const int chain = b >> 2, w = b & 3;
    const int seq = chain >> 1, dir = chain & 1;
    const int tid = threadIdx.x;
    const int r = tid >> 1;              // 0..255: gate-row within WG
    const int khalf = tid & 1;           // 0/1: which 128-wide k half
    const int g = r >> 6, jloc = r & 63;
    const int o = g * 256 + (w << 6) + jloc;   // row in [0,1024)

    __shared__ __align__(16) float hprev[256];
    __shared__ float gbuf[256];

    // Register-resident weight slice: Whh[dir][o][128*khalf .. +128)
    float wreg[128];
    {
        const float* wrow = Whh + (((size_t)(dir * 1024 + o)) << 8) + (khalf << 7);
#pragma unroll
        for (int q = 0; q < 32; ++q) {
            float4 v = *(const float4*)(wrow + 4 * q);
            wreg[4*q+0] = v.x; wreg[4*q+1] = v.y; wreg[4*q+2] = v.z; wreg[4*q+3] = v.w;
        }
    }
    if (tid < 256) hprev[tid] = 0.f;
    float cstate = 0.f;
    __syncthreads();

    for (int s = 0; s < 384; ++s) {
        const int t = dir ? (383 - s) : s;
        const float* pre_t = (layer == 0)
            ? pre + ((size_t)(seq * 2 + dir) * 384 + t) * 1024
            : pre + (((size_t)(seq * 384 + t)) * 2 + dir) * 1024;
        float pval = pre_t[o];   // both lanes of a pair load same addr (broadcast)

        // Full-k matvec for this thread's k-half of row o.
        float acc = 0.f;
        const float4* h4 = (const float4*)(hprev + (khalf << 7));
#pragma unroll
        for (int q = 0; q < 32; ++q) {
            float4 hv = h4[q];
            acc += wreg[4*q+0] * hv.x + wreg[4*q+1] * hv.y
                 + wreg[4*q+2] * hv.z + wreg[4*q+3] * hv.w;
        }
        acc += __shfl_xor(acc, 1);       // pair-reduce the two k-halves

        if (khalf == 0) {
            float gval = acc + pval;
            gbuf[r] = (g == 2) ? tanhf(gval) : 1.f / (1.f + expf(-gval));
        }
        __syncthreads();

        unsigned long long* pb = pub + (((size_t)chain * 2 + (s & 1)) * 4) * 64;
        if (tid < 64) {
            float iv = gbuf[tid], fv = gbuf[64 + tid];
            float gv = gbuf[128 + tid], ov = gbuf[192 + tid];
            cstate = fv * cstate + iv * gv;
            float h = ov * tanhf(cstate);
            hprev[(w << 6) + tid] = h;
            unsigned long long pk =
                ((unsigned long long)(unsigned)(s + 1) << 32) | __float_as_uint(h);
            __hip_atomic_store(&pb[w * 64 + tid], pk,
                               __ATOMIC_RELAXED, __HIP_MEMORY_SCOPE_AGENT);
            out[((size_t)seq * 384 + t) * 512 + dir * 256 + (w << 6) + tid] = h;
        } else if (tid < 256) {
            int u = tid - 64;
            int sl = u >> 6;
            int wp = (w + 1 + sl) & 3;
            int jl = u & 63;
            const unsigned long long* src = &pb[wp * 64 + jl];
            unsigned long long v;
            const unsigned expect = (unsigned)(s + 1);
            do {
                v = __hip_atomic_load(src, __ATOMIC_RELAXED, __HIP_MEMORY_SCOPE_AGENT);
            } while ((unsigned)(v >> 32) != expect);
            hprev[(wp << 6) + jl] = __uint_as_float((unsigned)v);
        }
        __syncthreads();
    }
}

// ---------------------------------------------------------------------------
// Generic NT GEMM: C[M][N] = act(scale * A[M][K] @ W[N][K]^T + bias[N])
// ---------------------------------------------------------------------------
__global__ __launch_bounds__(256) void gemm_nt_kernel(
    const float* __restrict__ A, const float* __restrict__ W,
    const float* __restrict__ bias, float* __restrict__ C,
    int M, int N, int K, float scale, int do_relu)
{
    __shared__ float As[32][68];
    __shared__ float Ws[32][68];
    const int tid = threadIdx.x;
    const int n0 = blockIdx.x * 64, m0 = blockIdx.y * 64;
    const int lr = tid >> 2;
    const int lk = (tid & 3) * 8;
    const int tm = tid >> 4, tn = tid & 15;
    float acc[4][4];
#pragma unroll
    for (int i = 0; i < 4; ++i)
#pragma unroll
        for (int j = 0; j < 4; ++j) acc[i][j] = 0.f;

    for (int kc = 0; kc < K; kc += 32) {
        float4 a0 = *(const float4*)(A + (size_t)(m0 + lr) * K + kc + lk);
        float4 a1 = *(const float4*)(A + (size_t)(m0 + lr) * K + kc + lk + 4);
        float4 w0 = *(const float4*)(W + (size_t)(n0 + lr) * K + kc + lk);
        float4 w1 = *(const float4*)(W + (size_t)(n0 + lr) * K + kc + lk + 4);
        __syncthreads();
        As[lk + 0][lr] = a0.x; As[lk + 1][lr] = a0.y; As[lk + 2][lr] = a0.z; As[lk + 3][lr] = a0.w;
        As[lk + 4][lr] = a1.x; As[lk + 5][lr] = a1.y; As[lk + 6][lr] = a1.z; As[lk + 7][lr] = a1.w;
        Ws[lk + 0][lr] = w0.x; Ws[lk + 1][lr] = w0.y; Ws[lk + 2][lr] = w0.z; Ws[lk + 3][lr] = w0.w;
        Ws[lk + 4][lr] = w1.x; Ws[lk + 5][lr] = w1.y; Ws[lk + 6][lr] = w1.z; Ws[lk + 7][lr] = w1.w;
        __syncthreads();
#pragma unroll
        for (int kk = 0; kk < 32; ++kk) {
            float4 av = *(const float4*)&As[kk][tm * 4];
            float4 wv = *(const float4*)&Ws[kk][tn * 4];
            acc[0][0] += av.x * wv.x; acc[0][1] += av.x * wv.y; acc[0][2] += av.x * wv.z; acc[0][3] += av.x * wv.w;
            acc[1][0] += av.y * wv.x; acc[1][1] += av.y * wv.y; acc[1][2] += av.y * wv.z; acc[1][3] += av.y * wv.w;
            acc[2][0] += av.z * wv.x; acc[2][1] += av.z * wv.y; acc[2][2] += av.z * wv.z; acc[2][3] += av.z * wv.w;
            acc[3][0] += av.w * wv.x; acc[3][1] += av.w * wv.y; acc[3][2] += av.w * wv.z; acc[3][3] += av.w * wv.w;
        }
    }
    float4 bv = make_float4(0.f, 0.f, 0.f, 0.f);
    if (bias) bv = *(const float4*)(bias + n0 + tn * 4);
#pragma unroll
    for (int i = 0; i < 4; ++i) {
        int m = m0 + tm * 4 + i;
        float4 v;
        v.x = scale * acc[i][0] + bv.x;
        v.y = scale * acc[i][1] + bv.y;
        v.z = scale * acc[i][2] + bv.z;
        v.w = scale * acc[i][3] + bv.w;
        if (do_relu) {
            v.x = fmaxf(v.x, 0.f); v.y = fmaxf(v.y, 0.f);
            v.z = fmaxf(v.z, 0.f); v.w = fmaxf(v.w, 0.f);
        }
        *(float4*)(C + (size_t)m * N + n0 + tn * 4) = v;
    }
}

// ---------------------------------------------------------------------------
// pairwise: out[i][j][:] = log_softmax( sum_c relu(ur'[i][c]+ul[j][c]) * woutT[c][:] + bout )
// ---------------------------------------------------------------------------
__global__ __launch_bounds__(256) void pairwise_kernel(
    const float* __restrict__ u,      // [768][1024]
    const float* __restrict__ woutT,  // [1024][2]
    const float* __restrict__ bout,   // [2]
    float* __restrict__ out)          // [384][384][2]
{
    __shared__ float Ur[32][128];
    __shared__ float Ul[32][128];
    __shared__ float Wo[256];
    const int tid = threadIdx.x;
    const int j0 = blockIdx.x * 32, i0 = blockIdx.y * 32;
    const int ii = tid >> 4, jj = tid & 15;
    const int il0 = ii * 2, il1 = ii * 2 + 1;
    const int jl0 = jj * 2, jl1 = jj * 2 + 1;
    float acc000 = 0.f, acc001 = 0.f, acc010 = 0.f, acc011 = 0.f;
    float acc100 = 0.f, acc101 = 0.f, acc110 = 0.f, acc111 = 0.f;
    const int lrw = tid >> 3;
    const int lcb = (tid & 7) * 16;

    for (int cc = 0; cc < 1024; cc += 128) {
        __syncthreads();
#pragma unroll
        for (int q = 0; q < 4; ++q) {
            *(float4*)&Ur[lrw][lcb + 4 * q] =
                *(const float4*)(u + (size_t)(i0 + lrw) * 1024 + cc + lcb + 4 * q);
            *(float4*)&Ul[lrw][lcb + 4 * q] =
                *(const float4*)(u + (size_t)(384 + j0 + lrw) * 1024 + cc + lcb + 4 * q);
        }
        if (tid < 128)
            *(float2*)&Wo[tid * 2] = *(const float2*)(woutT + (size_t)(cc + tid) * 2);
        __syncthreads();

        for (int c = 0; c < 128; c += 4) {
            float4 a0  = *(const float4*)&Ur[il0][c];
            float4 a1  = *(const float4*)&Ur[il1][c];
            float4 b0v = *(const float4*)&Ul[jl0][c];
            float4 b1v = *(const float4*)&Ul[jl1][c];
            float4 wA4 = *(const float4*)&Wo[c * 2];
            float4 wB4 = *(const float4*)&Wo[c * 2 + 4];
#define PW_STEP(AX, W0, W1)                                   \
            { float rr;                                       \
              rr = fmaxf(a0.AX + b0v.AX, 0.f); acc000 += rr*(W0); acc001 += rr*(W1); \
              rr = fmaxf(a0.AX + b1v.AX, 0.f); acc010 += rr*(W0); acc011 += rr*(W1); \
              rr = fmaxf(a1.AX + b0v.AX, 0.f); acc100 += rr*(W0); acc101 += rr*(W1); \
              rr = fmaxf(a1.AX + b1v.AX, 0.f); acc110 += rr*(W0); acc111 += rr*(W1); }
            PW_STEP(x, wA4.x, wA4.y)
            PW_STEP(y, wA4.z, wA4.w)
            PW_STEP(z, wB4.x, wB4.y)
            PW_STEP(w, wB4.z, wB4.w)
#undef PW_STEP
        }
    }
    float2 bo = *(const float2*)bout;
    float pa[2][2][2] = {{{acc000, acc001}, {acc010, acc011}},
                         {{acc100, acc101}, {acc110, acc111}}};
#pragma unroll
    for (int pi = 0; pi < 2; ++pi)
#pragma unroll
        for (int pj = 0; pj < 2; ++pj) {
            float l0 = pa[pi][pj][0] + bo.x;
            float l1 = pa[pi][pj][1] + bo.y;
            float m = fmaxf(l0, l1);
            float lse = m + logf(expf(l0 - m) + expf(l1 - m));
            int ig = i0 + il0 + pi;
            int jg = j0 + jl0 + pj;
            float2 o2; o2.x = l0 - lse; o2.y = l1 - lse;
            *(float2*)(out + ((size_t)ig * 384 + jg) * 2) = o2;
        }
}

// ---------------------------------------------------------------------------
extern "C" void kernel_launch(void* const* d_in, const int* in_sizes, int n_in,
                              void* d_out, int out_size, void* d_ws, size_t ws_size,
                              hipStream_t stream)
{
    const float* v_r  = (const float*)d_in[0];
    const float* v_l  = (const float*)d_in[1];
    const float* Wih0 = (const float*)d_in[2];
    const float* Whh0 = (const float*)d_in[3];
    const float* bih0 = (const float*)d_in[4];
    const float* bhh0 = (const float*)d_in[5];
    const float* Wih1 = (const float*)d_in[6];
    const float* Whh1 = (const float*)d_in[7];
    const float* bih1 = (const float*)d_in[8];
    const float* bhh1 = (const float*)d_in[9];
    const float* W1   = (const float*)d_in[10];
    const float* b1   = (const float*)d_in[11];
    const float* W2   = (const float*)d_in[12];
    const float* b2   = (const float*)d_in[13];
    const float* W3   = (const float*)d_in[14];
    const float* b3   = (const float*)d_in[15];
    const float* Wout = (const float*)d_in[16];
    const float* bout = (const float*)d_in[17];
    float* out = (float*)d_out;

    float* ws = (float*)d_ws;
    size_t off = 0;
    float* b0sum = ws + off; off += 2048;
    float* b1sum = ws + off; off += 2048;
    float* W3sum = ws + off; off += 1024 * 512;
    float* woutT = ws + off; off += 2048;
    float* pre0  = ws + off; off += (size_t)4 * 384 * 1024;
    float* out0  = ws + off; off += (size_t)2 * 384 * 512;
    float* pre1  = ws + off; off += (size_t)768 * 2048;
    float* out1  = ws + off; off += (size_t)2 * 384 * 512;
    float* h1    = ws + off; off += (size_t)768 * 1024;
    float* h2    = ws + off; off += (size_t)768 * 512;
    float* u     = ws + off; off += (size_t)768 * 1024;
    unsigned long long* pub0 = (unsigned long long*)(ws + off); off += 4 * 2 * 4 * 64 * 2;
    unsigned long long* pub1 = (unsigned long long*)(ws + off); off += 4 * 2 * 4 * 64 * 2;

    prep_kernel<<<512, 256, 0, stream>>>(bih0, bhh0, bih1, bhh1, W3, Wout,
                                         b0sum, b1sum, W3sum, woutT);
    proj0_kernel<<<dim3(384, 4), 256, 0, stream>>>(v_r, v_l, Wih0, b0sum, pre0);
    lstm_rec_kernel<<<16, 512, 0, stream>>>(Whh0, pre0, out0, pub0, 0);
    gemm_nt_kernel<<<dim3(2048 / 64, 768 / 64), 256, 0, stream>>>(
        out0, Wih1, b1sum, pre1, 768, 2048, 512, 1.f, 0);
    lstm_rec_kernel<<<16, 512, 0, stream>>>(Whh1, pre1, out1, pub1, 1);
    gemm_nt_kernel<<<dim3(1024 / 64, 768 / 64), 256, 0, stream>>>(
        out1, W1, b1, h1, 768, 1024, 512, 1.f, 1);
    gemm_nt_kernel<<<dim3(512 / 64, 768 / 64), 256, 0, stream>>>(
        h1, W2, b2, h2, 768, 512, 1024, 1.f, 1);
    gemm_nt_kernel<<<dim3(1024 / 64, 384 / 64), 256, 0, stream>>>(
        h2, W3sum, b3, u, 384, 1024, 512, 0.5f, 0);
    gemm_nt_kernel<<<dim3(1024 / 64, 384 / 64), 256, 0, stream>>>(
        h2 + (size_t)384 * 512, W3sum, nullptr, u + (size_t)384 * 1024, 384, 1024, 512, 0.5f, 0);
    pairwise_kernel<<<dim3(12, 12), 256, 0, stream>>>(u, woutT, bout, out);
}

// Round 5
// 1916.501 us; speedup vs baseline: 1.2958x; 1.1073x over previous
//
#include <hip/hip_runtime.h>
#include <math.h>

// Problem constants
// H=256, D_IN=22, T=384, 4H=1024, N_R=N_L=384, H1=1024, H2=512, H3=1024, RRI=2

// ---------------------------------------------------------------------------
// prep: b0sum = bih0+bhh0, b1sum = bih1+bhh1, W3sum[n][k] = W3[n][k]+W3[n][512+k],
//       woutT[2c+k] = Wout[k][c]
// ---------------------------------------------------------------------------
__global__ __launch_bounds__(256) void prep_kernel(
    const float* __restrict__ bih0, const float* __restrict__ bhh0,
    const float* __restrict__ bih1, const float* __restrict__ bhh1,
    const float* __restrict__ W3,   const float* __restrict__ Wout,
    float* __restrict__ b0sum, float* __restrict__ b1sum,
    float* __restrict__ W3sum, float* __restrict__ woutT)
{
    int idx = blockIdx.x * 256 + threadIdx.x;
    int stride = gridDim.x * 256;
    if (idx < 2048) {
        b0sum[idx] = bih0[idx] + bhh0[idx];
        b1sum[idx] = bih1[idx] + bhh1[idx];
        woutT[idx] = Wout[(idx & 1) * 1024 + (idx >> 1)];
    }
    for (int i = idx; i < 1024 * 512; i += stride) {
        int n = i >> 9, k = i & 511;
        W3sum[i] = W3[n * 1024 + k] + W3[n * 1024 + 512 + k];
    }
}

// ---------------------------------------------------------------------------
// proj0: pre0[(seq*2+dir)][t][o] = x[t] @ Wih0[dir].T + b0sum[dir]
// ---------------------------------------------------------------------------
__global__ __launch_bounds__(256) void proj0_kernel(
    const float* __restrict__ v_r, const float* __restrict__ v_l,
    const float* __restrict__ Wih0, const float* __restrict__ b0sum,
    float* __restrict__ pre0)
{
    int t = blockIdx.x;
    int sd = blockIdx.y;            // seq*2 + dir
    int seq = sd >> 1, dir = sd & 1;
    const float* x = (seq ? v_l : v_r) + t * 22;
    __shared__ float sx[22];
    if (threadIdx.x < 22) sx[threadIdx.x] = x[threadIdx.x];
    __syncthreads();
#pragma unroll
    for (int q = 0; q < 4; ++q) {
        int o = q * 256 + threadIdx.x;
        const float* wr = Wih0 + (size_t)(dir * 1024 + o) * 22;
        float acc = b0sum[dir * 1024 + o];
#pragma unroll
        for (int d = 0; d < 22; ++d) acc += sx[d] * wr[d];
        pre0[((size_t)sd * 384 + t) * 1024 + o] = acc;
    }
}

// ---------------------------------------------------------------------------
// LSTM recurrence, v5. 16 blocks x 512 threads; 4 WGs/chain (R2-proven),
// WG (chain,w) owns h-outputs j in [64w, 64w+64).
//
// Matvec mapping (v4's win, 4x less LDS traffic than R2):
//   thread t: ks = t&7 (32-wide k-slice), r = t>>3 (h-output j=(w<<6)+r);
//   holds ALL 4 gate rows for j over its k-slice = 128 fp32 weights, PINNED
//   via empty asm (R2 failure: LLVM remat'd loop-invariant loads -> VGPR 88,
//   weights re-streamed from L2 every step). shfl_xor over the 8 k-lanes,
//   ks==0 lane drops the 4 gate sums into gbuf (terminating, no cross-WG wait).
//
// ROLE SEPARATION BY WAVE (the R3/R4 fix): after the mid barrier,
//   wave 0 (tid<64)       = update + publish  (never waits on any peer)
//   waves 4-6 (256..447)  = poll peers' tagged publishes
// R3 hang / R4 stale-read root cause: writer lanes and poller lanes shared a
// wave; exec-mask branch serialization ran polls before writes -> cross-WG
// circular wait. With whole-wave roles, induction over steps gives
// deadlock-freedom (step-s publish depends only on step s-1 polls).
//
// h in LDS: 8 segments of 32 floats, stride 36 -> the 8 distinct ds_read_b128
// addrs tile all 32 banks (R2: 6.3M conflicts -> ~0).
// Cross-WG: tagged 8-byte publishes (tag<<32|h_bits), parity double-buffer
// (publishing s+2 implies all WGs consumed step s). Spin BOUNDED with s_sleep
// backoff: a protocol bug degrades to absmax error, never a hang.
// ---------------------------------------------------------------------------
__global__ __launch_bounds__(512, 2) void lstm_rec_kernel(
    const float* __restrict__ Whh,   // [2][1024][256]
    const float* __restrict__ pre,   // layer0: [(seq*2+dir)][384][1024]; layer1: [(seq*384+t)][2][1024]
    float* __restrict__ out,         // [2][384][512]  (cols: dir*256 + j)
    unsigned long long* pub,         // [4 chains][2 parity][256]
    int layer)
{
    const int b = blockIdx.x;
    const int chain = b >> 2, w = b & 3;
    const int seq = chain >> 1, dir = chain & 1;
    const int tid = threadIdx.x;
    const int ks = tid & 7;                  // k-slice [32ks, 32ks+32)
    const int r = tid >> 3;                  // 0..63
    const int j = (w << 6) + r;              // h index this thread's weights serve

    __shared__ __align__(16) float hpad[8 * 36];
    __shared__ float gbuf[256];              // [gate][64] post-reduction sums

    // Pinned register weights: gate rows {g*256+j}, k in [32ks, 32ks+32).
    float4 wt[4][8];
#pragma unroll
    for (int g = 0; g < 4; ++g) {
        const float4* wv = (const float4*)(
            Whh + (((size_t)(dir * 1024 + g * 256 + j)) << 8) + (ks << 5));
#pragma unroll
        for (int q = 0; q < 8; ++q) wt[g][q] = wv[q];
    }
#pragma unroll
    for (int g = 0; g < 4; ++g)
#pragma unroll
        for (int q = 0; q < 8; ++q)
            asm volatile("" : "+v"(wt[g][q].x), "+v"(wt[g][q].y),
                              "+v"(wt[g][q].z), "+v"(wt[g][q].w));

    if (tid < 8 * 36) hpad[tid] = 0.f;
    float cstate = 0.f;                      // live in wave 0 (tid<64): j=(w<<6)+tid
    __syncthreads();

    for (int s = 0; s < 384; ++s) {
        const int t = dir ? (383 - s) : s;
        const float* pre_t = (layer == 0)
            ? pre + ((size_t)(seq * 2 + dir) * 384 + t) * 1024
            : pre + (((size_t)(seq * 384 + t)) * 2 + dir) * 1024;
        // Writer wave issues its pre loads early (latency hidden by matvec).
        float pg0 = 0.f, pg1 = 0.f, pg2 = 0.f, pg3 = 0.f;
        if (tid < 64) {
            const int jw = (w << 6) + tid;
            pg0 = pre_t[jw];
            pg1 = pre_t[256 + jw];
            pg2 = pre_t[512 + jw];
            pg3 = pre_t[768 + jw];
        }

        // Matvec: 4 gate rows x 32 k; h-slice read once (8 x ds_read_b128).
        float a0 = 0.f, a1 = 0.f, a2 = 0.f, a3 = 0.f;
        const float4* h4 = (const float4*)(hpad + 36 * ks);
#pragma unroll
        for (int q = 0; q < 8; ++q) {
            float4 hv = h4[q];
            a0 += wt[0][q].x * hv.x + wt[0][q].y * hv.y + wt[0][q].z * hv.z + wt[0][q].w * hv.w;
            a1 += wt[1][q].x * hv.x + wt[1][q].y * hv.y + wt[1][q].z * hv.z + wt[1][q].w * hv.w;
            a2 += wt[2][q].x * hv.x + wt[2][q].y * hv.y + wt[2][q].z * hv.z + wt[2][q].w * hv.w;
            a3 += wt[3][q].x * hv.x + wt[3][q].y * hv.y + wt[3][q].z * hv.z + wt[3][q].w * hv.w;
        }
#pragma unroll
        for (int d = 1; d < 8; d <<= 1) {
            a0 += __shfl_xor(a0, d);
            a1 += __shfl_xor(a1, d);
            a2 += __shfl_xor(a2, d);
            a3 += __shfl_xor(a3, d);
        }
        if (ks == 0) {                       // terminating divergence, no wait
            gbuf[r]       = a0;
            gbuf[64 + r]  = a1;
            gbuf[128 + r] = a2;
            gbuf[192 + r] = a3;
        }
        __syncthreads();                     // gate sums visible; hpad reads done

        unsigned long long* pb = pub + ((size_t)chain * 2 + (s & 1)) * 256;
        if (tid < 64) {
            // WAVE 0: update + publish. Depends on nothing cross-WG.
            const int jw = (w << 6) + tid;
            float iv = 1.f / (1.f + expf(-(gbuf[tid] + pg0)));
            float fv = 1.f / (1.f + expf(-(gbuf[64 + tid] + pg1)));
            float gv = tanhf(gbuf[128 + tid] + pg2);
            float ov = 1.f / (1.f + expf(-(gbuf[192 + tid] + pg3)));
            cstate = fv * cstate + iv * gv;
            float h = ov * tanhf(cstate);
            hpad[36 * (jw >> 5) + (jw & 31)] = h;
            unsigned long long pk =
                ((unsigned long long)(unsigned)(s + 1) << 32) | __float_as_uint(h);
            __hip_atomic_store(&pb[jw], pk, __ATOMIC_RELAXED, __HIP_MEMORY_SCOPE_AGENT);
            out[((size_t)seq * 384 + t) * 512 + dir * 256 + jw] = h;
        } else if (tid >= 256 && tid < 448) {
            // WAVES 4-6: poll the 3 peer WGs' 64-wide h slices.
            int cid = tid - 256;             // 0..191
            int peer = cid >> 6;             // 0..2
            int jl = cid & 63;
            int wp = (w + 1 + peer) & 3;
            int jr = (wp << 6) + jl;
            const unsigned long long* src = &pb[jr];
            const unsigned expect = (unsigned)(s + 1);
            unsigned long long v =
                __hip_atomic_load(src, __ATOMIC_RELAXED, __HIP_MEMORY_SCOPE_AGENT);
            if ((unsigned)(v >> 32) != expect) {
                for (int it = 0; it < 65536; ++it) {
                    __builtin_amdgcn_s_sleep(1);
                    v = __hip_atomic_load(src, __ATOMIC_RELAXED, __HIP_MEMORY_SCOPE_AGENT);
                    if ((unsigned)(v >> 32) == expect) break;
                }
            }
            hpad[36 * (jr >> 5) + (jr & 31)] = __uint_as_float((unsigned)v);
        }
        __syncthreads();
    }
}

// ---------------------------------------------------------------------------
// Generic NT GEMM: C[M][N] = act(scale * A[M][K] @ W[N][K]^T + bias[N])
// ---------------------------------------------------------------------------
__global__ __launch_bounds__(256) void gemm_nt_kernel(
    const float* __restrict__ A, const float* __restrict__ W,
    const float* __restrict__ bias, float* __restrict__ C,
    int M, int N, int K, float scale, int do_relu)
{
    __shared__ float As[32][68];
    __shared__ float Ws[32][68];
    const int tid = threadIdx.x;
    const int n0 = blockIdx.x * 64, m0 = blockIdx.y * 64;
    const int lr = tid >> 2;
    const int lk = (tid & 3) * 8;
    const int tm = tid >> 4, tn = tid & 15;
    float acc[4][4];
#pragma unroll
    for (int i = 0; i < 4; ++i)
#pragma unroll
        for (int j = 0; j < 4; ++j) acc[i][j] = 0.f;

    for (int kc = 0; kc < K; kc += 32) {
        float4 a0 = *(const float4*)(A + (size_t)(m0 + lr) * K + kc + lk);
        float4 a1 = *(const float4*)(A + (size_t)(m0 + lr) * K + kc + lk + 4);
        float4 w0 = *(const float4*)(W + (size_t)(n0 + lr) * K + kc + lk);
        float4 w1 = *(const float4*)(W + (size_t)(n0 + lr) * K + kc + lk + 4);
        __syncthreads();
        As[lk + 0][lr] = a0.x; As[lk + 1][lr] = a0.y; As[lk + 2][lr] = a0.z; As[lk + 3][lr] = a0.w;
        As[lk + 4][lr] = a1.x; As[lk + 5][lr] = a1.y; As[lk + 6][lr] = a1.z; As[lk + 7][lr] = a1.w;
        Ws[lk + 0][lr] = w0.x; Ws[lk + 1][lr] = w0.y; Ws[lk + 2][lr] = w0.z; Ws[lk + 3][lr] = w0.w;
        Ws[lk + 4][lr] = w1.x; Ws[lk + 5][lr] = w1.y; Ws[lk + 6][lr] = w1.z; Ws[lk + 7][lr] = w1.w;
        __syncthreads();
#pragma unroll
        for (int kk = 0; kk < 32; ++kk) {
            float4 av = *(const float4*)&As[kk][tm * 4];
            float4 wv = *(const float4*)&Ws[kk][tn * 4];
            acc[0][0] += av.x * wv.x; acc[0][1] += av.x * wv.y; acc[0][2] += av.x * wv.z; acc[0][3] += av.x * wv.w;
            acc[1][0] += av.y * wv.x; acc[1][1] += av.y * wv.y; acc[1][2] += av.y * wv.z; acc[1][3] += av.y * wv.w;
            acc[2][0] += av.z * wv.x; acc[2][1] += av.z * wv.y; acc[2][2] += av.z * wv.z; acc[2][3] += av.z * wv.w;
            acc[3][0] += av.w * wv.x; acc[3][1] += av.w * wv.y; acc[3][2] += av.w * wv.z; acc[3][3] += av.w * wv.w;
        }
    }
    float4 bv = make_float4(0.f, 0.f, 0.f, 0.f);
    if (bias) bv = *(const float4*)(bias + n0 + tn * 4);
#pragma unroll
    for (int i = 0; i < 4; ++i) {
        int m = m0 + tm * 4 + i;
        float4 v;
        v.x = scale * acc[i][0] + bv.x;
        v.y = scale * acc[i][1] + bv.y;
        v.z = scale * acc[i][2] + bv.z;
        v.w = scale * acc[i][3] + bv.w;
        if (do_relu) {
            v.x = fmaxf(v.x, 0.f); v.y = fmaxf(v.y, 0.f);
            v.z = fmaxf(v.z, 0.f); v.w = fmaxf(v.w, 0.f);
        }
        *(float4*)(C + (size_t)m * N + n0 + tn * 4) = v;
    }
}

// ---------------------------------------------------------------------------
// pairwise: out[i][j][:] = log_softmax( sum_c relu(ur'[i][c]+ul[j][c]) * woutT[c][:] + bout )
// ---------------------------------------------------------------------------
__global__ __launch_bounds__(256) void pairwise_kernel(
    const float* __restrict__ u,      // [768][1024]
    const float* __restrict__ woutT,  // [1024][2]
    const float* __restrict__ bout,   // [2]
    float* __restrict__ out)          // [384][384][2]
{
    __shared__ float Ur[32][128];
    __shared__ float Ul[32][128];
    __shared__ float Wo[256];
    const int tid = threadIdx.x;
    const int j0 = blockIdx.x * 32, i0 = blockIdx.y * 32;
    const int ii = tid >> 4, jj = tid & 15;
    const int il0 = ii * 2, il1 = ii * 2 + 1;
    const int jl0 = jj * 2, jl1 = jj * 2 + 1;
    float acc000 = 0.f, acc001 = 0.f, acc010 = 0.f, acc011 = 0.f;
    float acc100 = 0.f, acc101 = 0.f, acc110 = 0.f, acc111 = 0.f;
    const int lrw = tid >> 3;
    const int lcb = (tid & 7) * 16;

    for (int cc = 0; cc < 1024; cc += 128) {
        __syncthreads();
#pragma unroll
        for (int q = 0; q < 4; ++q) {
            *(float4*)&Ur[lrw][lcb + 4 * q] =
                *(const float4*)(u + (size_t)(i0 + lrw) * 1024 + cc + lcb + 4 * q);
            *(float4*)&Ul[lrw][lcb + 4 * q] =
                *(const float4*)(u + (size_t)(384 + j0 + lrw) * 1024 + cc + lcb + 4 * q);
        }
        if (tid < 128)
            *(float2*)&Wo[tid * 2] = *(const float2*)(woutT + (size_t)(cc + tid) * 2);
        __syncthreads();

        for (int c = 0; c < 128; c += 4) {
            float4 a0  = *(const float4*)&Ur[il0][c];
            float4 a1  = *(const float4*)&Ur[il1][c];
            float4 b0v = *(const float4*)&Ul[jl0][c];
            float4 b1v = *(const float4*)&Ul[jl1][c];
            float4 wA4 = *(const float4*)&Wo[c * 2];
            float4 wB4 = *(const float4*)&Wo[c * 2 + 4];
#define PW_STEP(AX, W0, W1)                                   \
            { float rr;                                       \
              rr = fmaxf(a0.AX + b0v.AX, 0.f); acc000 += rr*(W0); acc001 += rr*(W1); \
              rr = fmaxf(a0.AX + b1v.AX, 0.f); acc010 += rr*(W0); acc011 += rr*(W1); \
              rr = fmaxf(a1.AX + b0v.AX, 0.f); acc100 += rr*(W0); acc101 += rr*(W1); \
              rr = fmaxf(a1.AX + b1v.AX, 0.f); acc110 += rr*(W0); acc111 += rr*(W1); }
            PW_STEP(x, wA4.x, wA4.y)
            PW_STEP(y, wA4.z, wA4.w)
            PW_STEP(z, wB4.x, wB4.y)
            PW_STEP(w, wB4.z, wB4.w)
#undef PW_STEP
        }
    }
    float2 bo = *(const float2*)bout;
    float pa[2][2][2] = {{{acc000, acc001}, {acc010, acc011}},
                         {{acc100, acc101}, {acc110, acc111}}};
#pragma unroll
    for (int pi = 0; pi < 2; ++pi)
#pragma unroll
        for (int pj = 0; pj < 2; ++pj) {
            float l0 = pa[pi][pj][0] + bo.x;
            float l1 = pa[pi][pj][1] + bo.y;
            float m = fmaxf(l0, l1);
            float lse = m + logf(expf(l0 - m) + expf(l1 - m));
            int ig = i0 + il0 + pi;
            int jg = j0 + jl0 + pj;
            float2 o2; o2.x = l0 - lse; o2.y = l1 - lse;
            *(float2*)(out + ((size_t)ig * 384 + jg) * 2) = o2;
        }
}

// ---------------------------------------------------------------------------
extern "C" void kernel_launch(void* const* d_in, const int* in_sizes, int n_in,
                              void* d_out, int out_size, void* d_ws, size_t ws_size,
                              hipStream_t stream)
{
    const float* v_r  = (const float*)d_in[0];
    const float* v_l  = (const float*)d_in[1];
    const float* Wih0 = (const float*)d_in[2];
    const float* Whh0 = (const float*)d_in[3];
    const float* bih0 = (const float*)d_in[4];
    const float* bhh0 = (const float*)d_in[5];
    const float* Wih1 = (const float*)d_in[6];
    const float* Whh1 = (const float*)d_in[7];
    const float* bih1 = (const float*)d_in[8];
    const float* bhh1 = (const float*)d_in[9];
    const float* W1   = (const float*)d_in[10];
    const float* b1   = (const float*)d_in[11];
    const float* W2   = (const float*)d_in[12];
    const float* b2   = (const float*)d_in[13];
    const float* W3   = (const float*)d_in[14];
    const float* b3   = (const float*)d_in[15];
    const float* Wout = (const float*)d_in[16];
    const float* bout = (const float*)d_in[17];
    float* out = (float*)d_out;

    float* ws = (float*)d_ws;
    size_t off = 0;
    float* b0sum = ws + off; off += 2048;
    float* b1sum = ws + off; off += 2048;
    float* W3sum = ws + off; off += 1024 * 512;
    float* woutT = ws + off; off += 2048;
    float* pre0  = ws + off; off += (size_t)4 * 384 * 1024;
    float* out0  = ws + off; off += (size_t)2 * 384 * 512;
    float* pre1  = ws + off; off += (size_t)768 * 2048;
    float* out1  = ws + off; off += (size_t)2 * 384 * 512;
    float* h1    = ws + off; off += (size_t)768 * 1024;
    float* h2    = ws + off; off += (size_t)768 * 512;
    float* u     = ws + off; off += (size_t)768 * 1024;
    unsigned long long* pub0 = (unsigned long long*)(ws + off); off += 4 * 2 * 256 * 2;
    unsigned long long* pub1 = (unsigned long long*)(ws + off); off += 4 * 2 * 256 * 2;

    prep_kernel<<<512, 256, 0, stream>>>(bih0, bhh0, bih1, bhh1, W3, Wout,
                                         b0sum, b1sum, W3sum, woutT);
    proj0_kernel<<<dim3(384, 4), 256, 0, stream>>>(v_r, v_l, Wih0, b0sum, pre0);
    lstm_rec_kernel<<<16, 512, 0, stream>>>(Whh0, pre0, out0, pub0, 0);
    gemm_nt_kernel<<<dim3(2048 / 64, 768 / 64), 256, 0, stream>>>(
        out0, Wih1, b1sum, pre1, 768, 2048, 512, 1.f, 0);
    lstm_rec_kernel<<<16, 512, 0, stream>>>(Whh1, pre1, out1, pub1, 1);
    gemm_nt_kernel<<<dim3(1024 / 64, 768 / 64), 256, 0, stream>>>(
        out1, W1, b1, h1, 768, 1024, 512, 1.f, 1);
    gemm_nt_kernel<<<dim3(512 / 64, 768 / 64), 256, 0, stream>>>(
        h1, W2, b2, h2, 768, 512, 1024, 1.f, 1);
    gemm_nt_kernel<<<dim3(1024 / 64, 384 / 64), 256, 0, stream>>>(
        h2, W3sum, b3, u, 384, 1024, 512, 0.5f, 0);
    gemm_nt_kernel<<<dim3(1024 / 64, 384 / 64), 256, 0, stream>>>(
        h2 + (size_t)384 * 512, W3sum, nullptr, u + (size_t)384 * 1024, 384, 1024, 512, 0.5f, 0);
    pairwise_kernel<<<dim3(12, 12), 256, 0, stream>>>(u, woutT, bout, out);
}

// Round 6
// 1694.201 us; speedup vs baseline: 1.4658x; 1.1312x over previous
//
#include <hip/hip_runtime.h>
#include <math.h>

// Problem constants
// H=256, D_IN=22, T=384, 4H=1024, N_R=N_L=384, H1=1024, H2=512, H3=1024, RRI=2

// ---------------------------------------------------------------------------
// prep: b0sum = bih0+bhh0, b1sum = bih1+bhh1, W3sum[n][k] = W3[n][k]+W3[n][512+k],
//       woutT[2c+k] = Wout[k][c]
// ---------------------------------------------------------------------------
__global__ __launch_bounds__(256) void prep_kernel(
    const float* __restrict__ bih0, const float* __restrict__ bhh0,
    const float* __restrict__ bih1, const float* __restrict__ bhh1,
    const float* __restrict__ W3,   const float* __restrict__ Wout,
    float* __restrict__ b0sum, float* __restrict__ b1sum,
    float* __restrict__ W3sum, float* __restrict__ woutT)
{
    int idx = blockIdx.x * 256 + threadIdx.x;
    int stride = gridDim.x * 256;
    if (idx < 2048) {
        b0sum[idx] = bih0[idx] + bhh0[idx];
        b1sum[idx] = bih1[idx] + bhh1[idx];
        woutT[idx] = Wout[(idx & 1) * 1024 + (idx >> 1)];
    }
    for (int i = idx; i < 1024 * 512; i += stride) {
        int n = i >> 9, k = i & 511;
        W3sum[i] = W3[n * 1024 + k] + W3[n * 1024 + 512 + k];
    }
}

// ---------------------------------------------------------------------------
// proj0: pre0[(seq*2+dir)][t][o] = x[t] @ Wih0[dir].T + b0sum[dir]
// ---------------------------------------------------------------------------
__global__ __launch_bounds__(256) void proj0_kernel(
    const float* __restrict__ v_r, const float* __restrict__ v_l,
    const float* __restrict__ Wih0, const float* __restrict__ b0sum,
    float* __restrict__ pre0)
{
    int t = blockIdx.x;
    int sd = blockIdx.y;            // seq*2 + dir
    int seq = sd >> 1, dir = sd & 1;
    const float* x = (seq ? v_l : v_r) + t * 22;
    __shared__ float sx[22];
    if (threadIdx.x < 22) sx[threadIdx.x] = x[threadIdx.x];
    __syncthreads();
#pragma unroll
    for (int q = 0; q < 4; ++q) {
        int o = q * 256 + threadIdx.x;
        const float* wr = Wih0 + (size_t)(dir * 1024 + o) * 22;
        float acc = b0sum[dir * 1024 + o];
#pragma unroll
        for (int d = 0; d < 22; ++d) acc += sx[d] * wr[d];
        pre0[((size_t)sd * 384 + t) * 1024 + o] = acc;
    }
}

// ---------------------------------------------------------------------------
// LSTM recurrence, v6 = v5 + XCD CO-LOCATION.
// R5 post-mortem: step = 4940 cyc, ~1600 VALU + ~3300 sync stall. With
// grid=16 and the blockIdx%8 XCD round-robin, a chain's 4 WGs sat on 4
// DIFFERENT XCDs -> every publish->poll was a cross-XCD coherence trip.
// Fix: launch 32 blocks; chain = b&7 (b&7>=4 exits), w = b>>3, so chain c's
// WGs = blocks {c, c+8, c+16, c+24} -> all on XCD c (if %8 mapping holds;
// if not, perf-neutral, correctness unaffected). Publish/poll then resolves
// in XCD-local L2 (~200-300 cyc RT vs ~1000-2000 cross-XCD).
//
// Everything else = v5 (proven):
// - thread t: ks=t&7 (32-wide k-slice), r=t>>3, j=(w<<6)+r; holds all 4 gate
//   rows = 128 fp32 weights, pinned via empty asm (anti-remat, R2 lesson).
// - shfl_xor over 8 k-lanes; ks==0 drops gate sums into gbuf (terminating).
// - ROLE SEPARATION BY WAVE (R3/R4 lesson: writers+pollers in one wave =
//   exec-mask circular wait): wave 0 = update+publish (never waits);
//   waves 4-6 = poll. Induction => deadlock-free.
// - hpad stride 36: 8 ds_read_b128 addrs tile all 32 banks (R5: conflicts=0).
// - tagged 8B publishes (tag<<32|h_bits), parity double-buffer; BOUNDED spin.
// ---------------------------------------------------------------------------
__global__ __launch_bounds__(512, 2) void lstm_rec_kernel(
    const float* __restrict__ Whh,   // [2][1024][256]
    const float* __restrict__ pre,   // layer0: [(seq*2+dir)][384][1024]; layer1: [(seq*384+t)][2][1024]
    float* __restrict__ out,         // [2][384][512]  (cols: dir*256 + j)
    unsigned long long* pub,         // [4 chains][2 parity][256]
    int layer)
{
    const int b = blockIdx.x;
    const int chain = b & 7;                 // = XCD id under %8 round-robin
    const int w = b >> 3;                    // 0..3
    if (chain >= 4) return;                  // 16 idle blocks exit
    const int seq = chain >> 1, dir = chain & 1;
    const int tid = threadIdx.x;
    const int ks = tid & 7;                  // k-slice [32ks, 32ks+32)
    const int r = tid >> 3;                  // 0..63
    const int j = (w << 6) + r;              // h index this thread's weights serve

    __shared__ __align__(16) float hpad[8 * 36];
    __shared__ float gbuf[256];              // [gate][64] post-reduction sums

    // Pinned register weights: gate rows {g*256+j}, k in [32ks, 32ks+32).
    float4 wt[4][8];
#pragma unroll
    for (int g = 0; g < 4; ++g) {
        const float4* wv = (const float4*)(
            Whh + (((size_t)(dir * 1024 + g * 256 + j)) << 8) + (ks << 5));
#pragma unroll
        for (int q = 0; q < 8; ++q) wt[g][q] = wv[q];
    }
#pragma unroll
    for (int g = 0; g < 4; ++g)
#pragma unroll
        for (int q = 0; q < 8; ++q)
            asm volatile("" : "+v"(wt[g][q].x), "+v"(wt[g][q].y),
                              "+v"(wt[g][q].z), "+v"(wt[g][q].w));

    if (tid < 8 * 36) hpad[tid] = 0.f;
    float cstate = 0.f;                      // live in wave 0 (tid<64)
    __syncthreads();

    for (int s = 0; s < 384; ++s) {
        const int t = dir ? (383 - s) : s;
        const float* pre_t = (layer == 0)
            ? pre + ((size_t)(seq * 2 + dir) * 384 + t) * 1024
            : pre + (((size_t)(seq * 384 + t)) * 2 + dir) * 1024;
        // Writer wave issues its pre loads early (latency hidden by matvec).
        float pg0 = 0.f, pg1 = 0.f, pg2 = 0.f, pg3 = 0.f;
        if (tid < 64) {
            const int jw = (w << 6) + tid;
            pg0 = pre_t[jw];
            pg1 = pre_t[256 + jw];
            pg2 = pre_t[512 + jw];
            pg3 = pre_t[768 + jw];
        }

        // Matvec: 4 gate rows x 32 k; h-slice read once (8 x ds_read_b128).
        float a0 = 0.f, a1 = 0.f, a2 = 0.f, a3 = 0.f;
        const float4* h4 = (const float4*)(hpad + 36 * ks);
#pragma unroll
        for (int q = 0; q < 8; ++q) {
            float4 hv = h4[q];
            a0 += wt[0][q].x * hv.x + wt[0][q].y * hv.y + wt[0][q].z * hv.z + wt[0][q].w * hv.w;
            a1 += wt[1][q].x * hv.x + wt[1][q].y * hv.y + wt[1][q].z * hv.z + wt[1][q].w * hv.w;
            a2 += wt[2][q].x * hv.x + wt[2][q].y * hv.y + wt[2][q].z * hv.z + wt[2][q].w * hv.w;
            a3 += wt[3][q].x * hv.x + wt[3][q].y * hv.y + wt[3][q].z * hv.z + wt[3][q].w * hv.w;
        }
#pragma unroll
        for (int d = 1; d < 8; d <<= 1) {
            a0 += __shfl_xor(a0, d);
            a1 += __shfl_xor(a1, d);
            a2 += __shfl_xor(a2, d);
            a3 += __shfl_xor(a3, d);
        }
        if (ks == 0) {                       // terminating divergence, no wait
            gbuf[r]       = a0;
            gbuf[64 + r]  = a1;
            gbuf[128 + r] = a2;
            gbuf[192 + r] = a3;
        }
        __syncthreads();                     // gate sums visible; hpad reads done

        unsigned long long* pb = pub + ((size_t)chain * 2 + (s & 1)) * 256;
        if (tid < 64) {
            // WAVE 0: update + publish. Depends on nothing cross-WG.
            const int jw = (w << 6) + tid;
            float iv = 1.f / (1.f + expf(-(gbuf[tid] + pg0)));
            float fv = 1.f / (1.f + expf(-(gbuf[64 + tid] + pg1)));
            float gv = tanhf(gbuf[128 + tid] + pg2);
            float ov = 1.f / (1.f + expf(-(gbuf[192 + tid] + pg3)));
            cstate = fv * cstate + iv * gv;
            float h = ov * tanhf(cstate);
            hpad[36 * (jw >> 5) + (jw & 31)] = h;
            unsigned long long pk =
                ((unsigned long long)(unsigned)(s + 1) << 32) | __float_as_uint(h);
            __hip_atomic_store(&pb[jw], pk, __ATOMIC_RELAXED, __HIP_MEMORY_SCOPE_AGENT);
            out[((size_t)seq * 384 + t) * 512 + dir * 256 + jw] = h;
        } else if (tid >= 256 && tid < 448) {
            // WAVES 4-6: poll the 3 peer WGs' 64-wide h slices (XCD-local L2).
            int cid = tid - 256;             // 0..191
            int peer = cid >> 6;             // 0..2
            int jl = cid & 63;
            int wp = (w + 1 + peer) & 3;
            int jr = (wp << 6) + jl;
            const unsigned long long* src = &pb[jr];
            const unsigned expect = (unsigned)(s + 1);
            unsigned long long v =
                __hip_atomic_load(src, __ATOMIC_RELAXED, __HIP_MEMORY_SCOPE_AGENT);
            if ((unsigned)(v >> 32) != expect) {
                for (int it = 0; it < 65536; ++it) {
                    __builtin_amdgcn_s_sleep(1);
                    v = __hip_atomic_load(src, __ATOMIC_RELAXED, __HIP_MEMORY_SCOPE_AGENT);
                    if ((unsigned)(v >> 32) == expect) break;
                }
            }
            hpad[36 * (jr >> 5) + (jr & 31)] = __uint_as_float((unsigned)v);
        }
        __syncthreads();
    }
}

// ---------------------------------------------------------------------------
// Generic NT GEMM: C[M][N] = act(scale * A[M][K] @ W[N][K]^T + bias[N])
// ---------------------------------------------------------------------------
__global__ __launch_bounds__(256) void gemm_nt_kernel(
    const float* __restrict__ A, const float* __restrict__ W,
    const float* __restrict__ bias, float* __restrict__ C,
    int M, int N, int K, float scale, int do_relu)
{
    __shared__ float As[32][68];
    __shared__ float Ws[32][68];
    const int tid = threadIdx.x;
    const int n0 = blockIdx.x * 64, m0 = blockIdx.y * 64;
    const int lr = tid >> 2;
    const int lk = (tid & 3) * 8;
    const int tm = tid >> 4, tn = tid & 15;
    float acc[4][4];
#pragma unroll
    for (int i = 0; i < 4; ++i)
#pragma unroll
        for (int j = 0; j < 4; ++j) acc[i][j] = 0.f;

    for (int kc = 0; kc < K; kc += 32) {
        float4 a0 = *(const float4*)(A + (size_t)(m0 + lr) * K + kc + lk);
        float4 a1 = *(const float4*)(A + (size_t)(m0 + lr) * K + kc + lk + 4);
        float4 w0 = *(const float4*)(W + (size_t)(n0 + lr) * K + kc + lk);
        float4 w1 = *(const float4*)(W + (size_t)(n0 + lr) * K + kc + lk + 4);
        __syncthreads();
        As[lk + 0][lr] = a0.x; As[lk + 1][lr] = a0.y; As[lk + 2][lr] = a0.z; As[lk + 3][lr] = a0.w;
        As[lk + 4][lr] = a1.x; As[lk + 5][lr] = a1.y; As[lk + 6][lr] = a1.z; As[lk + 7][lr] = a1.w;
        Ws[lk + 0][lr] = w0.x; Ws[lk + 1][lr] = w0.y; Ws[lk + 2][lr] = w0.z; Ws[lk + 3][lr] = w0.w;
        Ws[lk + 4][lr] = w1.x; Ws[lk + 5][lr] = w1.y; Ws[lk + 6][lr] = w1.z; Ws[lk + 7][lr] = w1.w;
        __syncthreads();
#pragma unroll
        for (int kk = 0; kk < 32; ++kk) {
            float4 av = *(const float4*)&As[kk][tm * 4];
            float4 wv = *(const float4*)&Ws[kk][tn * 4];
            acc[0][0] += av.x * wv.x; acc[0][1] += av.x * wv.y; acc[0][2] += av.x * wv.z; acc[0][3] += av.x * wv.w;
            acc[1][0] += av.y * wv.x; acc[1][1] += av.y * wv.y; acc[1][2] += av.y * wv.z; acc[1][3] += av.y * wv.w;
            acc[2][0] += av.z * wv.x; acc[2][1] += av.z * wv.y; acc[2][2] += av.z * wv.z; acc[2][3] += av.z * wv.w;
            acc[3][0] += av.w * wv.x; acc[3][1] += av.w * wv.y; acc[3][2] += av.w * wv.z; acc[3][3] += av.w * wv.w;
        }
    }
    float4 bv = make_float4(0.f, 0.f, 0.f, 0.f);
    if (bias) bv = *(const float4*)(bias + n0 + tn * 4);
#pragma unroll
    for (int i = 0; i < 4; ++i) {
        int m = m0 + tm * 4 + i;
        float4 v;
        v.x = scale * acc[i][0] + bv.x;
        v.y = scale * acc[i][1] + bv.y;
        v.z = scale * acc[i][2] + bv.z;
        v.w = scale * acc[i][3] + bv.w;
        if (do_relu) {
            v.x = fmaxf(v.x, 0.f); v.y = fmaxf(v.y, 0.f);
            v.z = fmaxf(v.z, 0.f); v.w = fmaxf(v.w, 0.f);
        }
        *(float4*)(C + (size_t)m * N + n0 + tn * 4) = v;
    }
}

// ---------------------------------------------------------------------------
// pairwise: out[i][j][:] = log_softmax( sum_c relu(ur'[i][c]+ul[j][c]) * woutT[c][:] + bout )
// ---------------------------------------------------------------------------
__global__ __launch_bounds__(256) void pairwise_kernel(
    const float* __restrict__ u,      // [768][1024]
    const float* __restrict__ woutT,  // [1024][2]
    const float* __restrict__ bout,   // [2]
    float* __restrict__ out)          // [384][384][2]
{
    __shared__ float Ur[32][128];
    __shared__ float Ul[32][128];
    __shared__ float Wo[256];
    const int tid = threadIdx.x;
    const int j0 = blockIdx.x * 32, i0 = blockIdx.y * 32;
    const int ii = tid >> 4, jj = tid & 15;
    const int il0 = ii * 2, il1 = ii * 2 + 1;
    const int jl0 = jj * 2, jl1 = jj * 2 + 1;
    float acc000 = 0.f, acc001 = 0.f, acc010 = 0.f, acc011 = 0.f;
    float acc100 = 0.f, acc101 = 0.f, acc110 = 0.f, acc111 = 0.f;
    const int lrw = tid >> 3;
    const int lcb = (tid & 7) * 16;

    for (int cc = 0; cc < 1024; cc += 128) {
        __syncthreads();
#pragma unroll
        for (int q = 0; q < 4; ++q) {
            *(float4*)&Ur[lrw][lcb + 4 * q] =
                *(const float4*)(u + (size_t)(i0 + lrw) * 1024 + cc + lcb + 4 * q);
            *(float4*)&Ul[lrw][lcb + 4 * q] =
                *(const float4*)(u + (size_t)(384 + j0 + lrw) * 1024 + cc + lcb + 4 * q);
        }
        if (tid < 128)
            *(float2*)&Wo[tid * 2] = *(const float2*)(woutT + (size_t)(cc + tid) * 2);
        __syncthreads();

        for (int c = 0; c < 128; c += 4) {
            float4 a0  = *(const float4*)&Ur[il0][c];
            float4 a1  = *(const float4*)&Ur[il1][c];
            float4 b0v = *(const float4*)&Ul[jl0][c];
            float4 b1v = *(const float4*)&Ul[jl1][c];
            float4 wA4 = *(const float4*)&Wo[c * 2];
            float4 wB4 = *(const float4*)&Wo[c * 2 + 4];
#define PW_STEP(AX, W0, W1)                                   \
            { float rr;                                       \
              rr = fmaxf(a0.AX + b0v.AX, 0.f); acc000 += rr*(W0); acc001 += rr*(W1); \
              rr = fmaxf(a0.AX + b1v.AX, 0.f); acc010 += rr*(W0); acc011 += rr*(W1); \
              rr = fmaxf(a1.AX + b0v.AX, 0.f); acc100 += rr*(W0); acc101 += rr*(W1); \
              rr = fmaxf(a1.AX + b1v.AX, 0.f); acc110 += rr*(W0); acc111 += rr*(W1); }
            PW_STEP(x, wA4.x, wA4.y)
            PW_STEP(y, wA4.z, wA4.w)
            PW_STEP(z, wB4.x, wB4.y)
            PW_STEP(w, wB4.z, wB4.w)
#undef PW_STEP
        }
    }
    float2 bo = *(const float2*)bout;
    float pa[2][2][2] = {{{acc000, acc001}, {acc010, acc011}},
                         {{acc100, acc101}, {acc110, acc111}}};
#pragma unroll
    for (int pi = 0; pi < 2; ++pi)
#pragma unroll
        for (int pj = 0; pj < 2; ++pj) {
            float l0 = pa[pi][pj][0] + bo.x;
            float l1 = pa[pi][pj][1] + bo.y;
            float m = fmaxf(l0, l1);
            float lse = m + logf(expf(l0 - m) + expf(l1 - m));
            int ig = i0 + il0 + pi;
            int jg = j0 + jl0 + pj;
            float2 o2; o2.x = l0 - lse; o2.y = l1 - lse;
            *(float2*)(out + ((size_t)ig * 384 + jg) * 2) = o2;
        }
}

// ---------------------------------------------------------------------------
extern "C" void kernel_launch(void* const* d_in, const int* in_sizes, int n_in,
                              void* d_out, int out_size, void* d_ws, size_t ws_size,
                              hipStream_t stream)
{
    const float* v_r  = (const float*)d_in[0];
    const float* v_l  = (const float*)d_in[1];
    const float* Wih0 = (const float*)d_in[2];
    const float* Whh0 = (const float*)d_in[3];
    const float* bih0 = (const float*)d_in[4];
    const float* bhh0 = (const float*)d_in[5];
    const float* Wih1 = (const float*)d_in[6];
    const float* Whh1 = (const float*)d_in[7];
    const float* bih1 = (const float*)d_in[8];
    const float* bhh1 = (const float*)d_in[9];
    const float* W1   = (const float*)d_in[10];
    const float* b1   = (const float*)d_in[11];
    const float* W2   = (const float*)d_in[12];
    const float* b2   = (const float*)d_in[13];
    const float* W3   = (const float*)d_in[14];
    const float* b3   = (const float*)d_in[15];
    const float* Wout = (const float*)d_in[16];
    const float* bout = (const float*)d_in[17];
    float* out = (float*)d_out;

    float* ws = (float*)d_ws;
    size_t off = 0;
    float* b0sum = ws + off; off += 2048;
    float* b1sum = ws + off; off += 2048;
    float* W3sum = ws + off; off += 1024 * 512;
    float* woutT = ws + off; off += 2048;
    float* pre0  = ws + off; off += (size_t)4 * 384 * 1024;
    float* out0  = ws + off; off += (size_t)2 * 384 * 512;
    float* pre1  = ws + off; off += (size_t)768 * 2048;
    float* out1  = ws + off; off += (size_t)2 * 384 * 512;
    float* h1    = ws + off; off += (size_t)768 * 1024;
    float* h2    = ws + off; off += (size_t)768 * 512;
    float* u     = ws + off; off += (size_t)768 * 1024;
    unsigned long long* pub0 = (unsigned long long*)(ws + off); off += 4 * 2 * 256 * 2;
    unsigned long long* pub1 = (unsigned long long*)(ws + off); off += 4 * 2 * 256 * 2;

    prep_kernel<<<512, 256, 0, stream>>>(bih0, bhh0, bih1, bhh1, W3, Wout,
                                         b0sum, b1sum, W3sum, woutT);
    proj0_kernel<<<dim3(384, 4), 256, 0, stream>>>(v_r, v_l, Wih0, b0sum, pre0);
    lstm_rec_kernel<<<32, 512, 0, stream>>>(Whh0, pre0, out0, pub0, 0);
    gemm_nt_kernel<<<dim3(2048 / 64, 768 / 64), 256, 0, stream>>>(
        out0, Wih1, b1sum, pre1, 768, 2048, 512, 1.f, 0);
    lstm_rec_kernel<<<32, 512, 0, stream>>>(Whh1, pre1, out1, pub1, 1);
    gemm_nt_kernel<<<dim3(1024 / 64, 768 / 64), 256, 0, stream>>>(
        out1, W1, b1, h1, 768, 1024, 512, 1.f, 1);
    gemm_nt_kernel<<<dim3(512 / 64, 768 / 64), 256, 0, stream>>>(
        h1, W2, b2, h2, 768, 512, 1024, 1.f, 1);
    gemm_nt_kernel<<<dim3(1024 / 64, 384 / 64), 256, 0, stream>>>(
        h2, W3sum, b3, u, 384, 1024, 512, 0.5f, 0);
    gemm_nt_kernel<<<dim3(1024 / 64, 384 / 64), 256, 0, stream>>>(
        h2 + (size_t)384 * 512, W3sum, nullptr, u + (size_t)384 * 1024, 384, 1024, 512, 0.5f, 0);
    pairwise_kernel<<<dim3(12, 12), 256, 0, stream>>>(u, woutT, bout, out);
}

// Round 7
// 1410.916 us; speedup vs baseline: 1.7601x; 1.2008x over previous
//
#include <hip/hip_runtime.h>
#include <math.h>

// Problem constants
// H=256, D_IN=22, T=384, 4H=1024, N_R=N_L=384, H1=1024, H2=512, H3=1024, RRI=2

typedef _Float16 half2_t __attribute__((ext_vector_type(2)));

__device__ __forceinline__ float fast_sig(float x) {
    // 1/(1+e^-x) via native v_exp_f32
    float e = __expf(-x);
    return __builtin_amdgcn_rcpf(1.f + e);
}
__device__ __forceinline__ float fast_tanh(float x) {
    x = fminf(fmaxf(x, -30.f), 30.f);
    float e = __expf(2.f * x);
    return (e - 1.f) * __builtin_amdgcn_rcpf(e + 1.f);
}

// ---------------------------------------------------------------------------
// prep: b0sum = bih0+bhh0, b1sum = bih1+bhh1, W3sum[n][k] = W3[n][k]+W3[n][512+k],
//       woutT[2c+k] = Wout[k][c]
// ---------------------------------------------------------------------------
__global__ __launch_bounds__(256) void prep_kernel(
    const float* __restrict__ bih0, const float* __restrict__ bhh0,
    const float* __restrict__ bih1, const float* __restrict__ bhh1,
    const float* __restrict__ W3,   const float* __restrict__ Wout,
    float* __restrict__ b0sum, float* __restrict__ b1sum,
    float* __restrict__ W3sum, float* __restrict__ woutT)
{
    int idx = blockIdx.x * 256 + threadIdx.x;
    int stride = gridDim.x * 256;
    if (idx < 2048) {
        b0sum[idx] = bih0[idx] + bhh0[idx];
        b1sum[idx] = bih1[idx] + bhh1[idx];
        woutT[idx] = Wout[(idx & 1) * 1024 + (idx >> 1)];
    }
    for (int i = idx; i < 1024 * 512; i += stride) {
        int n = i >> 9, k = i & 511;
        W3sum[i] = W3[n * 1024 + k] + W3[n * 1024 + 512 + k];
    }
}

// ---------------------------------------------------------------------------
// proj0: pre0[(seq*2+dir)][t][o] = x[t] @ Wih0[dir].T + b0sum[dir]
// ---------------------------------------------------------------------------
__global__ __launch_bounds__(256) void proj0_kernel(
    const float* __restrict__ v_r, const float* __restrict__ v_l,
    const float* __restrict__ Wih0, const float* __restrict__ b0sum,
    float* __restrict__ pre0)
{
    int t = blockIdx.x;
    int sd = blockIdx.y;            // seq*2 + dir
    int seq = sd >> 1, dir = sd & 1;
    const float* x = (seq ? v_l : v_r) + t * 22;
    __shared__ float sx[22];
    if (threadIdx.x < 22) sx[threadIdx.x] = x[threadIdx.x];
    __syncthreads();
#pragma unroll
    for (int q = 0; q < 4; ++q) {
        int o = q * 256 + threadIdx.x;
        const float* wr = Wih0 + (size_t)(dir * 1024 + o) * 22;
        float acc = b0sum[dir * 1024 + o];
#pragma unroll
        for (int d = 0; d < 22; ++d) acc += sx[d] * wr[d];
        pre0[((size_t)sd * 384 + t) * 1024 + o] = acc;
    }
}

// ---------------------------------------------------------------------------
// LSTM recurrence, v7: TWO WGs per chain (was 4), f16 weights + v_dot2_f32_f16.
// R6 post-mortem: step=4275 cyc; co-location only saved ~670 -> the serial
// chain (matvec + 3 shfl rounds + ocml expf/tanhf + publish/poll RT) dominates.
// This round: halve sync parties, shrink reduce to 2 rounds, fast gates.
//
// Grid 16, block 512. chain = b&7 (>=4 exits), w = b>>3 in {0,1} ->
// chain c's WGs = blocks {c, c+8} -> both on XCD c (heuristic, perf-only).
// Thread t: ks = t&3 (64-wide k-slice), r = t>>2 in [0,128): own h-output
// j = w*128 + r. Holds 4 gate rows x 64 k as f16 pairs: 128 VGPRs, PINNED
// (anti-remat, R2 lesson). fdot2 accumulates in fp32 (f16 products exact).
// Reduce: 2 shfl_xor rounds over the 4 k-lanes; ks==0 drops 4 gate sums to
// gbuf (terminating). ROLE SEPARATION BY WAVE (R3/R4 lesson):
//   waves 0-1 (tid<128)  = update + publish (never waits)
//   wave 4 (tid 256-319) = poll peer's 64 packets
// h in LDS as half2: 4 segments of 32 half2, stride 40 (80B) -> b128 reads
// of the 4 k-slices hit disjoint bank quads {0-3,20-23,8-11,28-31}.
// Publish: even writer lanes pack (h[j],h[j+1]) as half2 + tag<<32, one 8B
// relaxed agent atomic per pair; parity double-buffer; BOUNDED spin.
// Fast gates: __expf/rcp (native v_exp_f32) replace ocml expf/tanhf.
// ---------------------------------------------------------------------------
__global__ __launch_bounds__(512, 2) void lstm_rec_kernel(
    const float* __restrict__ Whh,   // [2][1024][256] fp32
    const float* __restrict__ pre,   // layer0: [(seq*2+dir)][384][1024]; layer1: [(seq*384+t)][2][1024]
    float* __restrict__ out,         // [2][384][512]  (cols: dir*256 + j)
    unsigned long long* pub,         // [4 chains][2 parity][128]
    int layer)
{
    const int b = blockIdx.x;
    const int chain = b & 7;                 // = XCD id under %8 round-robin
    const int w = b >> 3;                    // 0 or 1
    if (chain >= 4) return;
    const int seq = chain >> 1, dir = chain & 1;
    const int tid = threadIdx.x;
    const int ks = tid & 3;                  // k-slice [64ks, 64ks+64)
    const int r = tid >> 2;                  // 0..127
    const int j = (w << 7) + r;              // own h index in [0,256)

    __shared__ half2_t hh[4 * 40];           // 4 k-segments of 32 half2, stride 40
    __shared__ float gbuf[512];              // [gate][128] post-reduction sums

    // f16 weights, 4 gates x 32 half2, bit-stored in floats and pinned.
    float wt[4][32];
#pragma unroll
    for (int g = 0; g < 4; ++g) {
        const float* wrow = Whh + (((size_t)(dir * 1024 + g * 256 + j)) << 8) + (ks << 6);
#pragma unroll
        for (int q = 0; q < 32; ++q) {
            float2 v = *(const float2*)(wrow + 2 * q);
            half2_t h2;
            h2.x = (_Float16)v.x;
            h2.y = (_Float16)v.y;
            wt[g][q] = __builtin_bit_cast(float, h2);
        }
    }
#pragma unroll
    for (int g = 0; g < 4; ++g)
#pragma unroll
        for (int q = 0; q < 32; ++q)
            asm volatile("" : "+v"(wt[g][q]));

    if (tid < 160) hh[tid] = half2_t{(_Float16)0.f, (_Float16)0.f};
    float cstate = 0.f;                      // live in waves 0-1 (tid<128)
    __syncthreads();

    for (int s = 0; s < 384; ++s) {
        const int t = dir ? (383 - s) : s;
        const float* pre_t = (layer == 0)
            ? pre + ((size_t)(seq * 2 + dir) * 384 + t) * 1024
            : pre + (((size_t)(seq * 384 + t)) * 2 + dir) * 1024;
        // Writer waves issue pre loads early (latency hidden by matvec).
        float pg0 = 0.f, pg1 = 0.f, pg2 = 0.f, pg3 = 0.f;
        if (tid < 128) {
            const int jw = (w << 7) + tid;
            pg0 = pre_t[jw];
            pg1 = pre_t[256 + jw];
            pg2 = pre_t[512 + jw];
            pg3 = pre_t[768 + jw];
        }

        // Matvec: 4 gate rows x 64 k via fdot2; h-slice = 8 x ds_read_b128
        // (same addr for all lanes of equal ks -> LDS broadcast).
        float4 hl[8];
        {
            const float4* hb4 = (const float4*)(hh + 40 * ks);
#pragma unroll
            for (int m = 0; m < 8; ++m) hl[m] = hb4[m];
        }
        float a0 = 0.f, a1 = 0.f, a2 = 0.f, a3 = 0.f;
#pragma unroll
        for (int m = 0; m < 8; ++m) {
            const float he[4] = {hl[m].x, hl[m].y, hl[m].z, hl[m].w};
#pragma unroll
            for (int e = 0; e < 4; ++e) {
                half2_t hv = __builtin_bit_cast(half2_t, he[e]);
                int q = 4 * m + e;
                a0 = __builtin_amdgcn_fdot2(__builtin_bit_cast(half2_t, wt[0][q]), hv, a0, false);
                a1 = __builtin_amdgcn_fdot2(__builtin_bit_cast(half2_t, wt[1][q]), hv, a1, false);
                a2 = __builtin_amdgcn_fdot2(__builtin_bit_cast(half2_t, wt[2][q]), hv, a2, false);
                a3 = __builtin_amdgcn_fdot2(__builtin_bit_cast(half2_t, wt[3][q]), hv, a3, false);
            }
        }
#pragma unroll
        for (int d = 1; d < 4; d <<= 1) {
            a0 += __shfl_xor(a0, d);
            a1 += __shfl_xor(a1, d);
            a2 += __shfl_xor(a2, d);
            a3 += __shfl_xor(a3, d);
        }
        if (ks == 0) {                       // terminating divergence, no wait
            gbuf[r]       = a0;
            gbuf[128 + r] = a1;
            gbuf[256 + r] = a2;
            gbuf[384 + r] = a3;
        }
        __syncthreads();                     // gate sums visible; hh reads done

        unsigned long long* pb = pub + ((size_t)chain * 2 + (s & 1)) * 128;
        if (tid < 128) {
            // WAVES 0-1: update + publish. Depends on nothing cross-WG.
            const int jw = (w << 7) + tid;
            float iv = fast_sig(gbuf[tid] + pg0);
            float fv = fast_sig(gbuf[128 + tid] + pg1);
            float gv = fast_tanh(gbuf[256 + tid] + pg2);
            float ov = fast_sig(gbuf[384 + tid] + pg3);
            cstate = fv * cstate + iv * gv;
            float h = ov * fast_tanh(cstate);
            // own h -> LDS (f16 half of a half2 slot)
            _Float16 hf = (_Float16)h;
            unsigned hb = (unsigned)__builtin_bit_cast(unsigned short, hf);
            {
                int p = jw >> 1;
                int slot = 40 * (p >> 5) + (p & 31);
                ((__attribute__((address_space(3))) unsigned short*)hh)[2 * slot + (jw & 1)] =
                    (unsigned short)hb;
            }
            // publish pairs from even lanes: payload = h[j] | h[j+1]<<16
            unsigned up = (unsigned)__shfl_xor((int)hb, 1);
            if ((tid & 1) == 0) {
                unsigned payload = hb | (up << 16);
                unsigned long long pk =
                    ((unsigned long long)(unsigned)(s + 1) << 32) | payload;
                __hip_atomic_store(&pb[(w << 6) + (tid >> 1)], pk,
                                   __ATOMIC_RELAXED, __HIP_MEMORY_SCOPE_AGENT);
            }
            out[((size_t)seq * 384 + t) * 512 + dir * 256 + jw] = h;
        } else if (tid >= 256 && tid < 320) {
            // WAVE 4: poll the peer WG's 64 h-pair packets (XCD-local L2).
            int p = tid - 256;               // 0..63
            int wp = 1 - w;
            const unsigned long long* src = &pb[(wp << 6) + p];
            const unsigned expect = (unsigned)(s + 1);
            unsigned long long v =
                __hip_atomic_load(src, __ATOMIC_RELAXED, __HIP_MEMORY_SCOPE_AGENT);
            if ((unsigned)(v >> 32) != expect) {
                for (int it = 0; it < 65536; ++it) {
                    __builtin_amdgcn_s_sleep(1);
                    v = __hip_atomic_load(src, __ATOMIC_RELAXED, __HIP_MEMORY_SCOPE_AGENT);
                    if ((unsigned)(v >> 32) == expect) break;
                }
            }
            int pp = (wp << 6) + p;          // remote pair index
            hh[40 * (pp >> 5) + (pp & 31)] =
                __builtin_bit_cast(half2_t, (unsigned)v);
        }
        __syncthreads();
    }
}

// ---------------------------------------------------------------------------
// Generic NT GEMM: C[M][N] = act(scale * A[M][K] @ W[N][K]^T + bias[N])
// ---------------------------------------------------------------------------
__global__ __launch_bounds__(256) void gemm_nt_kernel(
    const float* __restrict__ A, const float* __restrict__ W,
    const float* __restrict__ bias, float* __restrict__ C,
    int M, int N, int K, float scale, int do_relu)
{
    __shared__ float As[32][68];
    __shared__ float Ws[32][68];
    const int tid = threadIdx.x;
    const int n0 = blockIdx.x * 64, m0 = blockIdx.y * 64;
    const int lr = tid >> 2;
    const int lk = (tid & 3) * 8;
    const int tm = tid >> 4, tn = tid & 15;
    float acc[4][4];
#pragma unroll
    for (int i = 0; i < 4; ++i)
#pragma unroll
        for (int j = 0; j < 4; ++j) acc[i][j] = 0.f;

    for (int kc = 0; kc < K; kc += 32) {
        float4 a0 = *(const float4*)(A + (size_t)(m0 + lr) * K + kc + lk);
        float4 a1 = *(const float4*)(A + (size_t)(m0 + lr) * K + kc + lk + 4);
        float4 w0 = *(const float4*)(W + (size_t)(n0 + lr) * K + kc + lk);
        float4 w1 = *(const float4*)(W + (size_t)(n0 + lr) * K + kc + lk + 4);
        __syncthreads();
        As[lk + 0][lr] = a0.x; As[lk + 1][lr] = a0.y; As[lk + 2][lr] = a0.z; As[lk + 3][lr] = a0.w;
        As[lk + 4][lr] = a1.x; As[lk + 5][lr] = a1.y; As[lk + 6][lr] = a1.z; As[lk + 7][lr] = a1.w;
        Ws[lk + 0][lr] = w0.x; Ws[lk + 1][lr] = w0.y; Ws[lk + 2][lr] = w0.z; Ws[lk + 3][lr] = w0.w;
        Ws[lk + 4][lr] = w1.x; Ws[lk + 5][lr] = w1.y; Ws[lk + 6][lr] = w1.z; Ws[lk + 7][lr] = w1.w;
        __syncthreads();
#pragma unroll
        for (int kk = 0; kk < 32; ++kk) {
            float4 av = *(const float4*)&As[kk][tm * 4];
            float4 wv = *(const float4*)&Ws[kk][tn * 4];
            acc[0][0] += av.x * wv.x; acc[0][1] += av.x * wv.y; acc[0][2] += av.x * wv.z; acc[0][3] += av.x * wv.w;
            acc[1][0] += av.y * wv.x; acc[1][1] += av.y * wv.y; acc[1][2] += av.y * wv.z; acc[1][3] += av.y * wv.w;
            acc[2][0] += av.z * wv.x; acc[2][1] += av.z * wv.y; acc[2][2] += av.z * wv.z; acc[2][3] += av.z * wv.w;
            acc[3][0] += av.w * wv.x; acc[3][1] += av.w * wv.y; acc[3][2] += av.w * wv.z; acc[3][3] += av.w * wv.w;
        }
    }
    float4 bv = make_float4(0.f, 0.f, 0.f, 0.f);
    if (bias) bv = *(const float4*)(bias + n0 + tn * 4);
#pragma unroll
    for (int i = 0; i < 4; ++i) {
        int m = m0 + tm * 4 + i;
        float4 v;
        v.x = scale * acc[i][0] + bv.x;
        v.y = scale * acc[i][1] + bv.y;
        v.z = scale * acc[i][2] + bv.z;
        v.w = scale * acc[i][3] + bv.w;
        if (do_relu) {
            v.x = fmaxf(v.x, 0.f); v.y = fmaxf(v.y, 0.f);
            v.z = fmaxf(v.z, 0.f); v.w = fmaxf(v.w, 0.f);
        }
        *(float4*)(C + (size_t)m * N + n0 + tn * 4) = v;
    }
}

// ---------------------------------------------------------------------------
// pairwise: out[i][j][:] = log_softmax( sum_c relu(ur'[i][c]+ul[j][c]) * woutT[c][:] + bout )
// R6 fix: 19.8M LDS conflicts came from Ul[2*jj][c] reads (16 rows x stride
// 128 -> banks 0-3, 16-way). Stride 132 + row remap (il=ii/ii+16, jl=jj/jj+16)
// -> row-base banks 4*idx mod 32 -> <=2-way (free).
// ---------------------------------------------------------------------------
__global__ __launch_bounds__(256) void pairwise_kernel(
    const float* __restrict__ u,      // [768][1024]
    const float* __restrict__ woutT,  // [1024][2]
    const float* __restrict__ bout,   // [2]
    float* __restrict__ out)          // [384][384][2]
{
    __shared__ float Ur[32][132];
    __shared__ float Ul[32][132];
    __shared__ float Wo[256];
    const int tid = threadIdx.x;
    const int j0 = blockIdx.x * 32, i0 = blockIdx.y * 32;
    const int ii = tid >> 4, jj = tid & 15;
    const int il0 = ii, il1 = ii + 16;
    const int jl0 = jj, jl1 = jj + 16;
    float acc000 = 0.f, acc001 = 0.f, acc010 = 0.f, acc011 = 0.f;
    float acc100 = 0.f, acc101 = 0.f, acc110 = 0.f, acc111 = 0.f;
    const int lrw = tid >> 3;
    const int lcb = (tid & 7) * 16;

    for (int cc = 0; cc < 1024; cc += 128) {
        __syncthreads();
#pragma unroll
        for (int q = 0; q < 4; ++q) {
            *(float4*)&Ur[lrw][lcb + 4 * q] =
                *(const float4*)(u + (size_t)(i0 + lrw) * 1024 + cc + lcb + 4 * q);
            *(float4*)&Ul[lrw][lcb + 4 * q] =
                *(const float4*)(u + (size_t)(384 + j0 + lrw) * 1024 + cc + lcb + 4 * q);
        }
        if (tid < 128)
            *(float2*)&Wo[tid * 2] = *(const float2*)(woutT + (size_t)(cc + tid) * 2);
        __syncthreads();

        for (int c = 0; c < 128; c += 4) {
            float4 a0  = *(const float4*)&Ur[il0][c];
            float4 a1  = *(const float4*)&Ur[il1][c];
            float4 b0v = *(const float4*)&Ul[jl0][c];
            float4 b1v = *(const float4*)&Ul[jl1][c];
            float4 wA4 = *(const float4*)&Wo[c * 2];
            float4 wB4 = *(const float4*)&Wo[c * 2 + 4];
#define PW_STEP(AX, W0, W1)                                   \
            { float rr;                                       \
              rr = fmaxf(a0.AX + b0v.AX, 0.f); acc000 += rr*(W0); acc001 += rr*(W1); \
              rr = fmaxf(a0.AX + b1v.AX, 0.f); acc010 += rr*(W0); acc011 += rr*(W1); \
              rr = fmaxf(a1.AX + b0v.AX, 0.f); acc100 += rr*(W0); acc101 += rr*(W1); \
              rr = fmaxf(a1.AX + b1v.AX, 0.f); acc110 += rr*(W0); acc111 += rr*(W1); }
            PW_STEP(x, wA4.x, wA4.y)
            PW_STEP(y, wA4.z, wA4.w)
            PW_STEP(z, wB4.x, wB4.y)
            PW_STEP(w, wB4.z, wB4.w)
#undef PW_STEP
        }
    }
    float2 bo = *(const float2*)bout;
    float pa[2][2][2] = {{{acc000, acc001}, {acc010, acc011}},
                         {{acc100, acc101}, {acc110, acc111}}};
#pragma unroll
    for (int pi = 0; pi < 2; ++pi)
#pragma unroll
        for (int pj = 0; pj < 2; ++pj) {
            float l0 = pa[pi][pj][0] + bo.x;
            float l1 = pa[pi][pj][1] + bo.y;
            float m = fmaxf(l0, l1);
            float lse = m + logf(expf(l0 - m) + expf(l1 - m));
            int ig = i0 + ii + 16 * pi;
            int jg = j0 + jj + 16 * pj;
            float2 o2; o2.x = l0 - lse; o2.y = l1 - lse;
            *(float2*)(out + ((size_t)ig * 384 + jg) * 2) = o2;
        }
}

// ---------------------------------------------------------------------------
extern "C" void kernel_launch(void* const* d_in, const int* in_sizes, int n_in,
                              void* d_out, int out_size, void* d_ws, size_t ws_size,
                              hipStream_t stream)
{
    const float* v_r  = (const float*)d_in[0];
    const float* v_l  = (const float*)d_in[1];
    const float* Wih0 = (const float*)d_in[2];
    const float* Whh0 = (const float*)d_in[3];
    const float* bih0 = (const float*)d_in[4];
    const float* bhh0 = (const float*)d_in[5];
    const float* Wih1 = (const float*)d_in[6];
    const float* Whh1 = (const float*)d_in[7];
    const float* bih1 = (const float*)d_in[8];
    const float* bhh1 = (const float*)d_in[9];
    const float* W1   = (const float*)d_in[10];
    const float* b1   = (const float*)d_in[11];
    const float* W2   = (const float*)d_in[12];
    const float* b2   = (const float*)d_in[13];
    const float* W3   = (const float*)d_in[14];
    const float* b3   = (const float*)d_in[15];
    const float* Wout = (const float*)d_in[16];
    const float* bout = (const float*)d_in[17];
    float* out = (float*)d_out;

    float* ws = (float*)d_ws;
    size_t off = 0;
    float* b0sum = ws + off; off += 2048;
    float* b1sum = ws + off; off += 2048;
    float* W3sum = ws + off; off += 1024 * 512;
    float* woutT = ws + off; off += 2048;
    float* pre0  = ws + off; off += (size_t)4 * 384 * 1024;
    float* out0  = ws + off; off += (size_t)2 * 384 * 512;
    float* pre1  = ws + off; off += (size_t)768 * 2048;
    float* out1  = ws + off; off += (size_t)2 * 384 * 512;
    float* h1    = ws + off; off += (size_t)768 * 1024;
    float* h2    = ws + off; off += (size_t)768 * 512;
    float* u     = ws + off; off += (size_t)768 * 1024;
    unsigned long long* pub0 = (unsigned long long*)(ws + off); off += 4 * 2 * 128 * 2;
    unsigned long long* pub1 = (unsigned long long*)(ws + off); off += 4 * 2 * 128 * 2;

    prep_kernel<<<512, 256, 0, stream>>>(bih0, bhh0, bih1, bhh1, W3, Wout,
                                         b0sum, b1sum, W3sum, woutT);
    proj0_kernel<<<dim3(384, 4), 256, 0, stream>>>(v_r, v_l, Wih0, b0sum, pre0);
    lstm_rec_kernel<<<16, 512, 0, stream>>>(Whh0, pre0, out0, pub0, 0);
    gemm_nt_kernel<<<dim3(2048 / 64, 768 / 64), 256, 0, stream>>>(
        out0, Wih1, b1sum, pre1, 768, 2048, 512, 1.f, 0);
    lstm_rec_kernel<<<16, 512, 0, stream>>>(Whh1, pre1, out1, pub1, 1);
    gemm_nt_kernel<<<dim3(1024 / 64, 768 / 64), 256, 0, stream>>>(
        out1, W1, b1, h1, 768, 1024, 512, 1.f, 1);
    gemm_nt_kernel<<<dim3(512 / 64, 768 / 64), 256, 0, stream>>>(
        h1, W2, b2, h2, 768, 512, 1024, 1.f, 1);
    gemm_nt_kernel<<<dim3(1024 / 64, 384 / 64), 256, 0, stream>>>(
        h2, W3sum, b3, u, 384, 1024, 512, 0.5f, 0);
    gemm_nt_kernel<<<dim3(1024 / 64, 384 / 64), 256, 0, stream>>>(
        h2 + (size_t)384 * 512, W3sum, nullptr, u + (size_t)384 * 1024, 384, 1024, 512, 0.5f, 0);
    pairwise_kernel<<<dim3(12, 12), 256, 0, stream>>>(u, woutT, bout, out);
}